// Round 7
// baseline (5921.891 us; speedup 1.0000x reference)
//
#include <hip/hip_runtime.h>
#include <hip/hip_bf16.h>
#include <math.h>

#define BATCH   8
#define NPTS    8192
#define MTOT    (BATCH * NPTS)   // 65536 rows
#define EPSV    1e-8f

// flags
#define F_RELU_OUT 1
#define F_RELU_A   2
#define F_ACCUM    4

// ---------------------------------------------------------------------------
// Per-(b,c) image stats: mean over H*W, unbiased var (ddof=1), scale=sqrt(var+eps)
__global__ __launch_bounds__(256) void stats_kernel(
    const float* __restrict__ feat, int HW,
    float* __restrict__ mean, float* __restrict__ scale)
{
    int bc = blockIdx.x;
    const float* p = feat + (size_t)bc * HW;
    float s = 0.f, s2 = 0.f;
    for (int i = threadIdx.x; i < HW; i += 256) {
        float v = p[i];
        s += v; s2 += v * v;
    }
    for (int off = 32; off; off >>= 1) {
        s  += __shfl_xor(s,  off);
        s2 += __shfl_xor(s2, off);
    }
    __shared__ float shs[4], shs2[4];
    int wave = threadIdx.x >> 6, lane = threadIdx.x & 63;
    if (lane == 0) { shs[wave] = s; shs2[wave] = s2; }
    __syncthreads();
    if (threadIdx.x == 0) {
        float S  = shs[0] + shs[1] + shs[2] + shs[3];
        float S2 = shs2[0] + shs2[1] + shs2[2] + shs2[3];
        float m = S / HW;
        float var = (S2 - HW * m * m) / (HW - 1);
        mean[bc]  = m;
        scale[bc] = sqrtf(var + EPSV);
    }
}

// ---------------------------------------------------------------------------
// Wc[m,n] = sum_k d1w[m, off+k] * t_w[k, n]   (M=512 rows, N=K=C)
__global__ __launch_bounds__(256) void matmul_small(
    const float* __restrict__ A, int lda,
    const float* __restrict__ Bm, int ldb,
    float* __restrict__ Cc, int C)
{
    int idx = blockIdx.x * 256 + threadIdx.x;
    int m = idx / C, n = idx % C;
    if (m >= 512) return;
    float s = 0.f;
    for (int k = 0; k < C; ++k)
        s += A[(size_t)m * lda + k] * Bm[(size_t)k * ldb + n];
    Cc[m * C + n] = s;
}

// bc[n] = sum_k d1w[n, off+k] * t_b[k]  (+ extra[n])
__global__ __launch_bounds__(64) void bias_combine(
    const float* __restrict__ d1w, int off, int C,
    const float* __restrict__ tb, const float* __restrict__ extra,
    float* __restrict__ out)
{
    int n = blockIdx.x * 64 + threadIdx.x;
    if (n >= 512) return;
    float s = extra ? extra[n] : 0.f;
    for (int k = 0; k < C; ++k)
        s += d1w[(size_t)n * 1923 + off + k] * tb[k];
    out[n] = s;
}

// ---------------------------------------------------------------------------
// C[Mc,N] (+)= A[Mc,K] @ W[N,K]^T + bias
__global__ __launch_bounds__(256) void gemm_kernel(
    const float* __restrict__ A, int lda,
    const float* __restrict__ W, int ldw,
    const float* __restrict__ bias,
    float* __restrict__ C, int ldc,
    int M, int N, int K, int flags)
{
    const int BM = 128, BN = 64, BK = 16, TM = 8, TN = 4;
    __shared__ float As[BK][BM + 4];
    __shared__ float Ws[BK][BN + 4];
    const int tid = threadIdx.x;
    const int bm = blockIdx.x * BM;
    const int bn = blockIdx.y * BN;
    const int tx = tid & 15;
    const int ty = tid >> 4;
    float acc[TM][TN] = {};

    for (int k0 = 0; k0 < K; k0 += BK) {
        #pragma unroll
        for (int idx = tid; idx < BM * BK; idx += 256) {
            int r = idx >> 4, k = idx & 15;
            float v = 0.f;
            if (k0 + k < K) v = A[(size_t)(bm + r) * lda + k0 + k];
            if (flags & F_RELU_A) v = fmaxf(v, 0.f);
            As[k][r] = v;
        }
        #pragma unroll
        for (int idx = tid; idx < BN * BK; idx += 256) {
            int r = idx >> 4, k = idx & 15;
            float v = 0.f;
            if (k0 + k < K) v = W[(size_t)(bn + r) * ldw + k0 + k];
            Ws[k][r] = v;
        }
        __syncthreads();
        #pragma unroll
        for (int kk = 0; kk < BK; ++kk) {
            float a[TM], b[TN];
            #pragma unroll
            for (int i = 0; i < TM; ++i) a[i] = As[kk][ty * TM + i];
            #pragma unroll
            for (int j = 0; j < TN; ++j) b[j] = Ws[kk][tx * TN + j];
            #pragma unroll
            for (int i = 0; i < TM; ++i)
                #pragma unroll
                for (int j = 0; j < TN; ++j)
                    acc[i][j] += a[i] * b[j];
        }
        __syncthreads();
    }

    #pragma unroll
    for (int i = 0; i < TM; ++i) {
        int m = bm + ty * TM + i;
        #pragma unroll
        for (int j = 0; j < TN; ++j) {
            int n = bn + tx * TN + j;
            float v = acc[i][j];
            if (bias) v += bias[n];
            if (flags & F_ACCUM) v += C[(size_t)m * ldc + n];
            if (flags & F_RELU_OUT) v = fmaxf(v, 0.f);
            C[(size_t)m * ldc + n] = v;
        }
    }
}

// ---------------------------------------------------------------------------
// AdaIN modulate; rows are chunk-local, row0 = global row offset of chunk.
__global__ __launch_bounds__(256) void adain_kernel(
    const float* __restrict__ pc, int C, int row0,
    const float* __restrict__ img_mean, const float* __restrict__ img_scale,
    float* __restrict__ out)
{
    int wave = threadIdx.x >> 6;
    int lane = threadIdx.x & 63;
    size_t row = (size_t)blockIdx.x * 4 + wave;
    int b = (int)((row0 + row) / NPTS);
    const float* x = pc + row * C;
    int nper = C >> 6;
    float vals[8];
    float s = 0.f, s2 = 0.f;
    for (int i = 0; i < nper; ++i) {
        float v = x[lane + (i << 6)];
        vals[i] = v; s += v; s2 += v * v;
    }
    for (int off = 32; off; off >>= 1) {
        s  += __shfl_xor(s,  off);
        s2 += __shfl_xor(s2, off);
    }
    float mean = s / C;
    float var = (s2 - C * mean * mean) / (C - 1);
    float inv = 1.f / sqrtf(var + EPSV);
    const float* im = img_mean + (size_t)b * C;
    const float* is_ = img_scale + (size_t)b * C;
    float* o = out + row * C;
    for (int i = 0; i < nper; ++i) {
        int c = lane + (i << 6);
        o[c] = ((vals[i] - mean) * inv + im[c]) * is_[c];
    }
}

// ---------------------------------------------------------------------------
// Projection + bilinear gather; chunk-local rows, row0 global offset.
__global__ __launch_bounds__(256) void proj_kernel(
    const float* __restrict__ points, const float* __restrict__ pm,
    const float* __restrict__ feat, int C, int H, int W, int row0, int Mc,
    float* __restrict__ out)
{
    size_t idx = (size_t)blockIdx.x * 256 + threadIdx.x;
    size_t total = (size_t)Mc * C;
    if (idx >= total) return;
    int c = (int)(idx % C);
    size_t m = idx / C;
    size_t gm = (size_t)row0 + m;
    int b = (int)(gm / NPTS);
    const float* p = points + gm * 3;
    const float* P = pm + (size_t)b * 16;
    float px = p[0], py = p[1], pz = p[2];
    float c0 = P[0]  * px + P[1]  * py + P[2]  * pz + P[3];
    float c1 = P[4]  * px + P[5]  * py + P[6]  * pz + P[7];
    float c3 = P[12] * px + P[13] * py + P[14] * pz + P[15];
    float x = (c0 / c3 + 1.f) * 0.5f;
    float y = 1.f - (c1 / c3 + 1.f) * 0.5f;
    float x0 = fminf(fmaxf(x * W, 0.f), (float)(W - 1));
    float y0 = fminf(fmaxf(y * H, 0.f), (float)(H - 1));
    float x1f = floorf(x0), x2f = ceilf(x0);
    float y1f = floorf(y0), y2f = ceilf(y0);
    int xi1 = (int)x1f, xi2 = (int)x2f, yi1 = (int)y1f, yi2 = (int)y2f;
    const float* fb = feat + ((size_t)b * C + c) * (size_t)(H * W);
    float Q11 = fb[yi1 * W + xi1];
    float Q12 = fb[yi2 * W + xi1];
    float Q21 = fb[yi1 * W + xi2];
    float Q22 = fb[yi2 * W + xi2];
    float wx2 = x2f - x0, wx1 = x0 - x1f;
    float wy2 = y2f - y0, wy1 = y0 - y1f;
    out[m * C + c] = wx2 * wy2 * Q11 + wx1 * wy2 * Q21
                   + wx2 * wy1 * Q12 + wx1 * wy1 * Q22;
}

// ---------------------------------------------------------------------------
// out[row0+m,:] = relu(x3[m,:]) @ d4w^T + d4b + points[row0+m,:]
__global__ __launch_bounds__(256) void final_kernel(
    const float* __restrict__ x3, const float* __restrict__ w,
    const float* __restrict__ bb, const float* __restrict__ points,
    int row0, int Mc, float* __restrict__ out)
{
    size_t m = (size_t)blockIdx.x * 256 + threadIdx.x;
    if (m >= (size_t)Mc) return;
    size_t gm = (size_t)row0 + m;
    float a0 = bb[0], a1 = bb[1], a2 = bb[2];
    const float* x = x3 + m * 128;
    #pragma unroll 4
    for (int k = 0; k < 128; ++k) {
        float v = fmaxf(x[k], 0.f);
        a0 += v * w[k];
        a1 += v * w[128 + k];
        a2 += v * w[256 + k];
    }
    out[gm * 3 + 0] = a0 + points[gm * 3 + 0];
    out[gm * 3 + 1] = a1 + points[gm * 3 + 1];
    out[gm * 3 + 2] = a2 + points[gm * 3 + 2];
}

// ---------------------------------------------------------------------------
extern "C" void kernel_launch(void* const* d_in, const int* in_sizes, int n_in,
                              void* d_out, int out_size, void* d_ws, size_t ws_size,
                              hipStream_t stream)
{
    const float* points = (const float*)d_in[0];
    const float* feat2  = (const float*)d_in[1];
    const float* feat3  = (const float*)d_in[2];
    const float* feat4  = (const float*)d_in[3];
    const float* feat5  = (const float*)d_in[4];
    const float* pmat   = (const float*)d_in[5];
    const float* b0w1 = (const float*)d_in[6];  const float* b0b1 = (const float*)d_in[7];
    const float* b0w2 = (const float*)d_in[8];  const float* b0b2 = (const float*)d_in[9];
    const float* t0w  = (const float*)d_in[10]; const float* t0b  = (const float*)d_in[11];
    const float* b1w1 = (const float*)d_in[12]; const float* b1b1 = (const float*)d_in[13];
    const float* b1w2 = (const float*)d_in[14]; const float* b1b2 = (const float*)d_in[15];
    const float* t1w  = (const float*)d_in[16]; const float* t1b  = (const float*)d_in[17];
    const float* b2w1 = (const float*)d_in[18]; const float* b2b1 = (const float*)d_in[19];
    const float* b2w2 = (const float*)d_in[20]; const float* b2b2 = (const float*)d_in[21];
    const float* t2w  = (const float*)d_in[22]; const float* t2b  = (const float*)d_in[23];
    const float* b3w1 = (const float*)d_in[24]; const float* b3b1 = (const float*)d_in[25];
    const float* b3w2 = (const float*)d_in[26]; const float* b3b2 = (const float*)d_in[27];
    const float* t3w  = (const float*)d_in[28]; const float* t3b  = (const float*)d_in[29];
    const float* d1w  = (const float*)d_in[30]; const float* d1b  = (const float*)d_in[31];
    const float* d2w  = (const float*)d_in[32]; const float* d2b  = (const float*)d_in[33];
    const float* d3w  = (const float*)d_in[34]; const float* d3b  = (const float*)d_in[35];
    const float* d4w  = (const float*)d_in[36]; const float* d4b  = (const float*)d_in[37];

    float* ws = (float*)d_ws;

    // ---- shared (chunk-invariant) region: folded weights, biases, stats ----
    const size_t WC_FLOATS   = 512 * 960;   // 491520
    const size_t BIAS_FLOATS = 512 * 4;
    const size_t STAT_FLOATS = 2 * 7680;
    const size_t SHARED = WC_FLOATS + BIAS_FLOATS + STAT_FLOATS;

    float* wc   = ws;
    float* wc0 = wc, *wc1 = wc0 + 512 * 64, *wc2 = wc1 + 512 * 128, *wc3 = wc2 + 512 * 256;
    float* biasc = wc + WC_FLOATS;
    float* bias0 = biasc, *bias1 = biasc + 512, *bias2 = biasc + 1024, *bias3 = biasc + 1536;
    float* smean = biasc + BIAS_FLOATS;
    float* sscale = smean + 7680;
    float* mean2 = smean, *mean3 = smean + 512, *mean4 = smean + 1536, *mean5 = smean + 3584;
    float* scl2 = sscale, *scl3 = sscale + 512, *scl4 = sscale + 1536, *scl5 = sscale + 3584;

    // ---- pick chunk count so per-chunk buffers fit in remaining ws ----
    const size_t PER_ROW = 64 + 128 + 256 + 512 + 512 + 512;  // 1984 floats
    size_t avail = (ws_size / 4 > SHARED) ? ws_size / 4 - SHARED : 0;
    int nch = 1;
    while (nch < 512 && (size_t)(MTOT / nch) * PER_ROW > avail) nch <<= 1;
    const int Mc = MTOT / nch;

    float* base = ws + SHARED;
    float* pc0  = base;                     // Mc*64
    float* pc1  = pc0  + (size_t)Mc * 64;   // Mc*128
    float* pc2  = pc1  + (size_t)Mc * 128;  // Mc*256
    float* pc3  = pc2  + (size_t)Mc * 256;  // Mc*512
    float* fbuf = pc3  + (size_t)Mc * 512;  // Mc*512
    float* x1   = fbuf + (size_t)Mc * 512;  // Mc*512
    float* x2   = pc2;                      // Mc*256 (pc2 dead by then)
    float* x3   = pc1;                      // Mc*128 (pc1 dead by then)

    // ---- chunk-invariant prep ----
    stats_kernel<<<8 * 64,  256, 0, stream>>>(feat2, 112 * 112, mean2, scl2);
    stats_kernel<<<8 * 128, 256, 0, stream>>>(feat3, 56 * 56,  mean3, scl3);
    stats_kernel<<<8 * 256, 256, 0, stream>>>(feat4, 28 * 28,  mean4, scl4);
    stats_kernel<<<8 * 512, 256, 0, stream>>>(feat5, 14 * 14,  mean5, scl5);

    matmul_small<<<(512 * 64 + 255) / 256, 256, 0, stream>>>(d1w + 0,   1923, t0w, 64,  wc0, 64);
    matmul_small<<<(512 * 128 + 255) / 256, 256, 0, stream>>>(d1w + 64,  1923, t1w, 128, wc1, 128);
    matmul_small<<<(512 * 256 + 255) / 256, 256, 0, stream>>>(d1w + 192, 1923, t2w, 256, wc2, 256);
    matmul_small<<<(512 * 512 + 255) / 256, 256, 0, stream>>>(d1w + 448, 1923, t3w, 512, wc3, 512);
    bias_combine<<<8, 64, 0, stream>>>(d1w, 0,   64,  t0b, d1b,     bias0);
    bias_combine<<<8, 64, 0, stream>>>(d1w, 64,  128, t1b, nullptr, bias1);
    bias_combine<<<8, 64, 0, stream>>>(d1w, 192, 256, t2b, nullptr, bias2);
    bias_combine<<<8, 64, 0, stream>>>(d1w, 448, 512, t3b, nullptr, bias3);

    auto gemm = [&](const float* A, int lda, const float* Wm, int ldw,
                    const float* bias, float* Cm, int ldc, int N, int K, int flags) {
        dim3 grid(Mc / 128, N / 64);
        gemm_kernel<<<grid, 256, 0, stream>>>(A, lda, Wm, ldw, bias, Cm, ldc,
                                              Mc, N, K, flags);
    };

    // ---- per-chunk pipeline ----
    for (int ch = 0; ch < nch; ++ch) {
        const int row0 = ch * Mc;
        const float* pts = points + (size_t)row0 * 3;

        // level 0
        gemm(pts, 3,  b0w1, 3,  b0b1, fbuf, 64, 64, 3,  F_RELU_OUT);
        gemm(fbuf, 64, b0w2, 64, b0b2, pc0,  64, 64, 64, F_RELU_OUT);
        adain_kernel<<<Mc / 4, 256, 0, stream>>>(pc0, 64, row0, mean2, scl2, fbuf);
        gemm(fbuf, 64, wc0, 64, bias0, x1, 512, 512, 64, 0);

        // level 1
        gemm(pc0, 64,  b1w1, 64,  b1b1, fbuf, 128, 128, 64,  F_RELU_OUT);
        gemm(fbuf, 128, b1w2, 128, b1b2, pc1, 128, 128, 128, F_RELU_OUT);
        adain_kernel<<<Mc / 4, 256, 0, stream>>>(pc1, 128, row0, mean3, scl3, fbuf);
        gemm(fbuf, 128, wc1, 128, bias1, x1, 512, 512, 128, F_ACCUM);

        // level 2
        gemm(pc1, 128, b2w1, 128, b2b1, fbuf, 256, 256, 128, F_RELU_OUT);
        gemm(fbuf, 256, b2w2, 256, b2b2, pc2, 256, 256, 256, F_RELU_OUT);
        adain_kernel<<<Mc / 4, 256, 0, stream>>>(pc2, 256, row0, mean4, scl4, fbuf);
        gemm(fbuf, 256, wc2, 256, bias2, x1, 512, 512, 256, F_ACCUM);

        // level 3
        gemm(pc2, 256, b3w1, 256, b3b1, fbuf, 512, 512, 256, F_RELU_OUT);
        gemm(fbuf, 512, b3w2, 512, b3b2, pc3, 512, 512, 512, F_RELU_OUT);
        adain_kernel<<<Mc / 4, 256, 0, stream>>>(pc3, 512, row0, mean5, scl5, fbuf);
        gemm(fbuf, 512, wc3, 512, bias3, x1, 512, 512, 512, F_ACCUM);

        // projections -> accumulate into x1 against raw d1w chunks
        size_t tot;
        tot = (size_t)Mc * 64;
        proj_kernel<<<(tot + 255) / 256, 256, 0, stream>>>(points, pmat, feat2, 64, 112, 112, row0, Mc, fbuf);
        gemm(fbuf, 64, d1w + 960, 1923, nullptr, x1, 512, 512, 64, F_ACCUM);
        tot = (size_t)Mc * 128;
        proj_kernel<<<(tot + 255) / 256, 256, 0, stream>>>(points, pmat, feat3, 128, 56, 56, row0, Mc, fbuf);
        gemm(fbuf, 128, d1w + 1024, 1923, nullptr, x1, 512, 512, 128, F_ACCUM);
        tot = (size_t)Mc * 256;
        proj_kernel<<<(tot + 255) / 256, 256, 0, stream>>>(points, pmat, feat4, 256, 28, 28, row0, Mc, fbuf);
        gemm(fbuf, 256, d1w + 1152, 1923, nullptr, x1, 512, 512, 256, F_ACCUM);
        tot = (size_t)Mc * 512;
        proj_kernel<<<(tot + 255) / 256, 256, 0, stream>>>(points, pmat, feat5, 512, 14, 14, row0, Mc, fbuf);
        gemm(fbuf, 512, d1w + 1408, 1923, nullptr, x1, 512, 512, 512, F_ACCUM);

        // points chunk
        gemm(pts, 3, d1w + 1920, 1923, nullptr, x1, 512, 512, 3, F_ACCUM);

        // head
        gemm(x1, 512, d2w, 512, d2b, x2, 256, 256, 512, F_RELU_A);
        gemm(x2, 256, d3w, 256, d3b, x3, 128, 128, 256, F_RELU_A);
        final_kernel<<<(Mc + 255) / 256, 256, 0, stream>>>(x3, d4w, d4b, points,
                                                           row0, Mc, (float*)d_out);
    }
}

// Round 9
// 2123.071 us; speedup vs baseline: 2.7893x; 2.7893x over previous
//
#include <hip/hip_runtime.h>
#include <hip/hip_bf16.h>
#include <math.h>

#define BATCH   8
#define NPTS    8192
#define MTOT    (BATCH * NPTS)   // 65536 rows
#define EPSV    1e-8f

typedef __hip_bfloat16 bf16;
typedef __attribute__((ext_vector_type(8))) short short8;
typedef __attribute__((ext_vector_type(4))) float f32x4;

// ---------------------------------------------------------------------------
// Per-(b,c) image stats (fp32 input): mean + sqrt(var_ddof1 + eps)
__global__ __launch_bounds__(256) void stats_kernel(
    const float* __restrict__ feat, int HW,
    float* __restrict__ mean, float* __restrict__ scale)
{
    int bc = blockIdx.x;
    const float* p = feat + (size_t)bc * HW;
    float s = 0.f, s2 = 0.f;
    for (int i = threadIdx.x; i < HW; i += 256) {
        float v = p[i];
        s += v; s2 += v * v;
    }
    for (int off = 32; off; off >>= 1) {
        s  += __shfl_xor(s,  off);
        s2 += __shfl_xor(s2, off);
    }
    __shared__ float shs[4], shs2[4];
    int wave = threadIdx.x >> 6, lane = threadIdx.x & 63;
    if (lane == 0) { shs[wave] = s; shs2[wave] = s2; }
    __syncthreads();
    if (threadIdx.x == 0) {
        float S  = shs[0] + shs[1] + shs[2] + shs[3];
        float S2 = shs2[0] + shs2[1] + shs2[2] + shs2[3];
        float m = S / HW;
        float var = (S2 - HW * m * m) / (HW - 1);
        mean[bc]  = m;
        scale[bc] = sqrtf(var + EPSV);
    }
}

// ---------------------------------------------------------------------------
// Folded weights: Wd1[m, off+n] = sum_k d1w[m, off+k] * t_w[k, n]  (bf16 out)
__global__ __launch_bounds__(256) void matmul_small(
    const float* __restrict__ A, int lda,
    const float* __restrict__ Bm, int ldb,
    bf16* __restrict__ Cc, int ldc, int C)
{
    int idx = blockIdx.x * 256 + threadIdx.x;
    int m = idx / C, n = idx % C;
    if (m >= 512) return;
    float s = 0.f;
    for (int k = 0; k < C; ++k)
        s += A[(size_t)m * lda + k] * Bm[(size_t)k * ldb + n];
    Cc[(size_t)m * ldc + n] = __float2bfloat16(s);
}

// biasTot[n] = extra[n] + sum_k d1w[n, off+k] * t_b[k]  (extra may alias out)
__global__ __launch_bounds__(64) void bias_combine(
    const float* __restrict__ d1w, int off, int C,
    const float* __restrict__ tb, const float* __restrict__ extra,
    float* __restrict__ out)
{
    int n = blockIdx.x * 64 + threadIdx.x;
    if (n >= 512) return;
    float s = extra[n];
    for (int k = 0; k < C; ++k)
        s += d1w[(size_t)n * 1923 + off + k] * tb[k];
    out[n] = s;
}

// ---------------------------------------------------------------------------
// Batched fp32->bf16 strided weight conversion (src==null -> fill zero)
struct ConvDesc { const float* src; bf16* dst; int srcLd, dstLd, rows, cols; };
struct ConvArgs { ConvDesc d[20]; int n; };

__global__ __launch_bounds__(256) void conv_batch(ConvArgs a)
{
    int di = blockIdx.y;
    if (di >= a.n) return;
    ConvDesc d = a.d[di];
    int total = d.rows * d.cols;
    for (int idx = blockIdx.x * 256 + threadIdx.x; idx < total;
         idx += gridDim.x * 256) {
        int r = idx / d.cols, c = idx % d.cols;
        float v = d.src ? d.src[(size_t)r * d.srcLd + c] : 0.f;
        d.dst[(size_t)r * d.dstLd + c] = __float2bfloat16(v);
    }
}

// ---------------------------------------------------------------------------
// bf16 MFMA GEMM: C[M,N] = relu(A[M,K] @ W[N,K]^T + bias), bf16 out.
// BM=128, BN template (64/128), BK=32, 256 threads (4 waves).
// Fragment mapping per learn_hip m89/m97: A lane: row=l&15, k=(l>>4)*8+j;
// B lane: col=l&15, k=(l>>4)*8+j; D: col=l&15, row=(l>>4)*4+q.
template<int BN>
__global__ __launch_bounds__(256) void gemm_bf16(
    const bf16* __restrict__ A, int lda,
    const bf16* __restrict__ W, int ldw,
    const float* __restrict__ bias,
    bf16* __restrict__ C, int ldc,
    int gx, int gy, int K)
{
    constexpr int LDK = 40;  // 32 + 8 pad (2-way LDS aliasing only)
    __shared__ __align__(16) bf16 As[128 * LDK];
    __shared__ __align__(16) bf16 Bs[BN * LDK];

    int nblk = gx * gy;
    int bid = blockIdx.x;
    if ((nblk & 7) == 0) {                 // XCD-chunked swizzle (T1)
        int cpx = nblk >> 3;
        bid = (bid & 7) * cpx + (bid >> 3);
    }
    const int bm = (bid / gy) * 128;
    const int bn = (bid % gy) * BN;

    const int tid = threadIdx.x;
    const int wave = tid >> 6, lane = tid & 63;
    constexpr int FM = (BN == 128) ? 4 : 2;
    constexpr int FN = 4;
    const int wm = (BN == 128) ? (wave >> 1) * 64 : wave * 32;
    const int wn = (BN == 128) ? (wave & 1) * 64 : 0;

    f32x4 acc[FM][FN] = {};

    const int arow = tid >> 1;
    const int akh  = (tid & 1) * 16;
    const int brow = (BN == 128) ? (tid >> 1) : (tid >> 2);
    const int bkh  = (BN == 128) ? (tid & 1) * 16 : (tid & 3) * 8;

    const int fr = lane & 15, kq = lane >> 4;

    for (int k0 = 0; k0 < K; k0 += 32) {
        {   // stage A: 16 bf16 (32B) per thread
            const uint4* src = reinterpret_cast<const uint4*>(
                A + (size_t)(bm + arow) * lda + k0 + akh);
            uint4 v0 = src[0], v1 = src[1];
            uint4* dst = reinterpret_cast<uint4*>(&As[arow * LDK + akh]);
            dst[0] = v0; dst[1] = v1;
        }
        if (BN == 128) {
            const uint4* src = reinterpret_cast<const uint4*>(
                W + (size_t)(bn + brow) * ldw + k0 + bkh);
            uint4 v0 = src[0], v1 = src[1];
            uint4* dst = reinterpret_cast<uint4*>(&Bs[brow * LDK + bkh]);
            dst[0] = v0; dst[1] = v1;
        } else {
            const uint4* src = reinterpret_cast<const uint4*>(
                W + (size_t)(bn + brow) * ldw + k0 + bkh);
            uint4 v0 = src[0];
            uint4* dst = reinterpret_cast<uint4*>(&Bs[brow * LDK + bkh]);
            dst[0] = v0;
        }
        __syncthreads();

        short8 a[FM], b[FN];
        #pragma unroll
        for (int i = 0; i < FM; ++i)
            a[i] = *reinterpret_cast<const short8*>(
                &As[(wm + i * 16 + fr) * LDK + kq * 8]);
        #pragma unroll
        for (int j = 0; j < FN; ++j)
            b[j] = *reinterpret_cast<const short8*>(
                &Bs[(wn + j * 16 + fr) * LDK + kq * 8]);
        #pragma unroll
        for (int i = 0; i < FM; ++i)
            #pragma unroll
            for (int j = 0; j < FN; ++j)
                acc[i][j] = __builtin_amdgcn_mfma_f32_16x16x32_bf16(
                    a[i], b[j], acc[i][j], 0, 0, 0);
        __syncthreads();
    }

    // epilogue: bias + relu -> bf16
    const int rq = lane >> 4;
    #pragma unroll
    for (int j = 0; j < FN; ++j) {
        int n = bn + wn + j * 16 + fr;
        float bv = bias[n];
        #pragma unroll
        for (int i = 0; i < FM; ++i) {
            int mbase = bm + wm + i * 16 + rq * 4;
            #pragma unroll
            for (int q = 0; q < 4; ++q) {
                float v = acc[i][j][q] + bv;
                v = fmaxf(v, 0.f);
                C[(size_t)(mbase + q) * ldc + n] = __float2bfloat16(v);
            }
        }
    }
}

// ---------------------------------------------------------------------------
// AdaIN modulate: bf16 in, bf16 out (strided into feats)
__global__ __launch_bounds__(256) void adain_kernel(
    const bf16* __restrict__ pc, int C, int row0,
    const float* __restrict__ img_mean, const float* __restrict__ img_scale,
    bf16* __restrict__ out, int ldout)
{
    int wave = threadIdx.x >> 6;
    int lane = threadIdx.x & 63;
    size_t row = (size_t)blockIdx.x * 4 + wave;
    int b = (int)((row0 + row) / NPTS);
    const bf16* x = pc + row * C;
    int nper = C >> 6;
    float vals[8];
    float s = 0.f, s2 = 0.f;
    for (int i = 0; i < nper; ++i) {
        float v = __bfloat162float(x[lane + (i << 6)]);
        vals[i] = v; s += v; s2 += v * v;
    }
    for (int off = 32; off; off >>= 1) {
        s  += __shfl_xor(s,  off);
        s2 += __shfl_xor(s2, off);
    }
    float mean = s / C;
    float var = (s2 - C * mean * mean) / (C - 1);
    float inv = 1.f / sqrtf(var + EPSV);
    const float* im = img_mean + (size_t)b * C;
    const float* is_ = img_scale + (size_t)b * C;
    bf16* o = out + row * ldout;
    for (int i = 0; i < nper; ++i) {
        int c = lane + (i << 6);
        o[c] = __float2bfloat16(((vals[i] - mean) * inv + im[c]) * is_[c]);
    }
}

// ---------------------------------------------------------------------------
// Projection + bilinear gather -> bf16 strided into feats
__global__ __launch_bounds__(256) void proj_kernel(
    const float* __restrict__ points, const float* __restrict__ pm,
    const float* __restrict__ feat, int C, int H, int W, int row0, int Mc,
    bf16* __restrict__ out, int ldout)
{
    size_t idx = (size_t)blockIdx.x * 256 + threadIdx.x;
    size_t total = (size_t)Mc * C;
    if (idx >= total) return;
    int c = (int)(idx % C);
    size_t m = idx / C;
    size_t gm = (size_t)row0 + m;
    int b = (int)(gm / NPTS);
    const float* p = points + gm * 3;
    const float* P = pm + (size_t)b * 16;
    float px = p[0], py = p[1], pz = p[2];
    float c0 = P[0]  * px + P[1]  * py + P[2]  * pz + P[3];
    float c1 = P[4]  * px + P[5]  * py + P[6]  * pz + P[7];
    float c3 = P[12] * px + P[13] * py + P[14] * pz + P[15];
    float x = (c0 / c3 + 1.f) * 0.5f;
    float y = 1.f - (c1 / c3 + 1.f) * 0.5f;
    float x0 = fminf(fmaxf(x * W, 0.f), (float)(W - 1));
    float y0 = fminf(fmaxf(y * H, 0.f), (float)(H - 1));
    float x1f = floorf(x0), x2f = ceilf(x0);
    float y1f = floorf(y0), y2f = ceilf(y0);
    int xi1 = (int)x1f, xi2 = (int)x2f, yi1 = (int)y1f, yi2 = (int)y2f;
    const float* fb = feat + ((size_t)b * C + c) * (size_t)(H * W);
    float Q11 = fb[yi1 * W + xi1];
    float Q12 = fb[yi2 * W + xi1];
    float Q21 = fb[yi1 * W + xi2];
    float Q22 = fb[yi2 * W + xi2];
    float wx2 = x2f - x0, wx1 = x0 - x1f;
    float wy2 = y2f - y0, wy1 = y0 - y1f;
    float r = wx2 * wy2 * Q11 + wx1 * wy2 * Q21
            + wx2 * wy1 * Q12 + wx1 * wy1 * Q22;
    out[m * ldout + c] = __float2bfloat16(r);
}

// ---------------------------------------------------------------------------
// copy 3 fp32 point coords per row into a bf16 buffer (cols 0..2)
__global__ __launch_bounds__(256) void copy3_kernel(
    const float* __restrict__ pts, int row0, int Mc,
    bf16* __restrict__ dst, int dld)
{
    int m = blockIdx.x * 256 + threadIdx.x;
    if (m >= Mc) return;
    const float* p = pts + (size_t)(row0 + m) * 3;
    bf16* d = dst + (size_t)m * dld;
    d[0] = __float2bfloat16(p[0]);
    d[1] = __float2bfloat16(p[1]);
    d[2] = __float2bfloat16(p[2]);
}

// ---------------------------------------------------------------------------
// out[row0+m,:] = x3[m,:] @ d4w^T + d4b + points[row0+m,:]   (x3 pre-relu'd)
__global__ __launch_bounds__(256) void final_kernel(
    const bf16* __restrict__ x3, const float* __restrict__ w,
    const float* __restrict__ bb, const float* __restrict__ points,
    int row0, int Mc, float* __restrict__ out)
{
    size_t m = (size_t)blockIdx.x * 256 + threadIdx.x;
    if (m >= (size_t)Mc) return;
    size_t gm = (size_t)row0 + m;
    float a0 = bb[0], a1 = bb[1], a2 = bb[2];
    const bf16* x = x3 + m * 128;
    #pragma unroll 4
    for (int k = 0; k < 128; ++k) {
        float v = __bfloat162float(x[k]);
        a0 += v * w[k];
        a1 += v * w[128 + k];
        a2 += v * w[256 + k];
    }
    out[gm * 3 + 0] = a0 + points[gm * 3 + 0];
    out[gm * 3 + 1] = a1 + points[gm * 3 + 1];
    out[gm * 3 + 2] = a2 + points[gm * 3 + 2];
}

// ---------------------------------------------------------------------------
extern "C" void kernel_launch(void* const* d_in, const int* in_sizes, int n_in,
                              void* d_out, int out_size, void* d_ws, size_t ws_size,
                              hipStream_t stream)
{
    const float* points = (const float*)d_in[0];
    const float* feat2  = (const float*)d_in[1];
    const float* feat3  = (const float*)d_in[2];
    const float* feat4  = (const float*)d_in[3];
    const float* feat5  = (const float*)d_in[4];
    const float* pmat   = (const float*)d_in[5];
    const float* b0w1 = (const float*)d_in[6];  const float* b0b1 = (const float*)d_in[7];
    const float* b0w2 = (const float*)d_in[8];  const float* b0b2 = (const float*)d_in[9];
    const float* t0w  = (const float*)d_in[10]; const float* t0b  = (const float*)d_in[11];
    const float* b1w1 = (const float*)d_in[12]; const float* b1b1 = (const float*)d_in[13];
    const float* b1w2 = (const float*)d_in[14]; const float* b1b2 = (const float*)d_in[15];
    const float* t1w  = (const float*)d_in[16]; const float* t1b  = (const float*)d_in[17];
    const float* b2w1 = (const float*)d_in[18]; const float* b2b1 = (const float*)d_in[19];
    const float* b2w2 = (const float*)d_in[20]; const float* b2b2 = (const float*)d_in[21];
    const float* t2w  = (const float*)d_in[22]; const float* t2b  = (const float*)d_in[23];
    const float* b3w1 = (const float*)d_in[24]; const float* b3b1 = (const float*)d_in[25];
    const float* b3w2 = (const float*)d_in[26]; const float* b3b2 = (const float*)d_in[27];
    const float* t3w  = (const float*)d_in[28]; const float* t3b  = (const float*)d_in[29];
    const float* d1w  = (const float*)d_in[30]; const float* d1b  = (const float*)d_in[31];
    const float* d2w  = (const float*)d_in[32]; const float* d2b  = (const float*)d_in[33];
    const float* d3w  = (const float*)d_in[34]; const float* d3b  = (const float*)d_in[35];
    const float* d4w  = (const float*)d_in[36]; const float* d4b  = (const float*)d_in[37];

    // ---- fp32 shared region ----
    float* wsf = (float*)d_ws;
    float* biasTot = wsf;                  // 512
    float* smean   = wsf + 512;            // 7680
    float* sscale  = smean + 7680;         // 7680
    const size_t F32_FLOATS = 512 + 2 * 7680;   // 15872
    float* mean2 = smean, *mean3 = smean + 512, *mean4 = smean + 1536, *mean5 = smean + 3584;
    float* scl2 = sscale, *scl3 = sscale + 512, *scl4 = sscale + 1536, *scl5 = sscale + 3584;

    // ---- bf16 shared region: packed weights ----
    bf16* wb = (bf16*)(wsf + F32_FLOATS);
    bf16* Wd1   = wb;                       // 512 x 1952
    bf16* b0w1p = Wd1   + (size_t)512 * 1952;  // 64 x 32 (cols 3..31 zero)
    bf16* b0w2b = b0w1p + 64 * 32;          // 64 x 64
    bf16* b1w1b = b0w2b + 64 * 64;          // 128 x 64
    bf16* b1w2b = b1w1b + 128 * 64;         // 128 x 128
    bf16* b2w1b = b1w2b + 128 * 128;        // 256 x 128
    bf16* b2w2b = b2w1b + 256 * 128;        // 256 x 256
    bf16* b3w1b = b2w2b + 256 * 256;        // 512 x 256
    bf16* b3w2b = b3w1b + 512 * 256;        // 512 x 512
    bf16* d2wb  = b3w2b + (size_t)512 * 512; // 256 x 512
    bf16* d3wb  = d2wb  + (size_t)256 * 512; // 128 x 256
    const size_t SHARED_BF = (size_t)512 * 1952 + 64 * 32 + 64 * 64 + 128 * 64
        + 128 * 128 + 256 * 128 + 256 * 256 + (size_t)512 * 256
        + (size_t)512 * 512 + (size_t)256 * 512 + 128 * 256;   // 1,685,504

    const size_t SHARED_BYTES = F32_FLOATS * 4 + SHARED_BF * 2;

    // ---- chunking: per-row bf16 = 32+512+64+128+256+512+1952+512+256+128 = 4352
    const size_t PER_ROW_BYTES = 4352 * 2;
    size_t avail = (ws_size > SHARED_BYTES) ? ws_size - SHARED_BYTES : 0;
    int nch = 1;
    while (nch < 512 && (size_t)(MTOT / nch) * PER_ROW_BYTES > avail) nch <<= 1;
    const int Mc = MTOT / nch;

    bf16* cb = wb + SHARED_BF;
    bf16* ptsb  = cb;                          // Mc x 32
    bf16* hbuf  = ptsb  + (size_t)Mc * 32;     // Mc x <=512
    bf16* pc0   = hbuf  + (size_t)Mc * 512;    // Mc x 64
    bf16* pc1   = pc0   + (size_t)Mc * 64;     // Mc x 128
    bf16* pc2   = pc1   + (size_t)Mc * 128;    // Mc x 256
    bf16* pc3   = pc2   + (size_t)Mc * 256;    // Mc x 512
    bf16* feats = pc3   + (size_t)Mc * 512;    // Mc x 1952
    bf16* x1r   = feats + (size_t)Mc * 1952;   // Mc x 512
    bf16* x2    = x1r   + (size_t)Mc * 512;    // Mc x 256
    bf16* x3    = x2    + (size_t)Mc * 256;    // Mc x 128

    // ---- prep: stats ----
    stats_kernel<<<8 * 64,  256, 0, stream>>>(feat2, 112 * 112, mean2, scl2);
    stats_kernel<<<8 * 128, 256, 0, stream>>>(feat3, 56 * 56,  mean3, scl3);
    stats_kernel<<<8 * 256, 256, 0, stream>>>(feat4, 28 * 28,  mean4, scl4);
    stats_kernel<<<8 * 512, 256, 0, stream>>>(feat5, 14 * 14,  mean5, scl5);

    // ---- prep: weight conversions (one batched launch) ----
    ConvArgs ca;
    int nd = 0;
    auto addc = [&](const float* s, bf16* d, int sld, int dld, int r, int c) {
        ca.d[nd++] = ConvDesc{ s, d, sld, dld, r, c };
    };
    addc(b0w1, b0w1p, 3, 32, 64, 3);
    addc(nullptr, b0w1p + 3, 0, 32, 64, 29);        // zero pad cols 3..31
    addc(b0w2, b0w2b, 64, 64, 64, 64);
    addc(b1w1, b1w1b, 64, 64, 128, 64);
    addc(b1w2, b1w2b, 128, 128, 128, 128);
    addc(b2w1, b2w1b, 128, 128, 256, 128);
    addc(b2w2, b2w2b, 256, 256, 256, 256);
    addc(b3w1, b3w1b, 256, 256, 512, 256);
    addc(b3w2, b3w2b, 512, 512, 512, 512);
    addc(d2w, d2wb, 512, 512, 256, 512);
    addc(d3w, d3wb, 256, 256, 128, 256);
    addc(d1w + 960,  Wd1 + 960,  1923, 1952, 512, 64);   // proj2 chunk
    addc(d1w + 1024, Wd1 + 1024, 1923, 1952, 512, 128);  // proj3
    addc(d1w + 1152, Wd1 + 1152, 1923, 1952, 512, 256);  // proj4
    addc(d1w + 1408, Wd1 + 1408, 1923, 1952, 512, 512);  // proj5
    addc(d1w + 1920, Wd1 + 1920, 1923, 1952, 512, 3);    // points cols
    addc(nullptr,    Wd1 + 1923, 0,    1952, 512, 29);   // zero pad 1923..1951
    ca.n = nd;
    conv_batch<<<dim3(64, nd), 256, 0, stream>>>(ca);

    // ---- prep: folded transform weights into Wd1 cols 0..959, biasTot ----
    matmul_small<<<(512 * 64 + 255) / 256, 256, 0, stream>>>(d1w + 0,   1923, t0w, 64,  Wd1 + 0,   1952, 64);
    matmul_small<<<(512 * 128 + 255) / 256, 256, 0, stream>>>(d1w + 64,  1923, t1w, 128, Wd1 + 64,  1952, 128);
    matmul_small<<<(512 * 256 + 255) / 256, 256, 0, stream>>>(d1w + 192, 1923, t2w, 256, Wd1 + 192, 1952, 256);
    matmul_small<<<(512 * 512 + 255) / 256, 256, 0, stream>>>(d1w + 448, 1923, t3w, 512, Wd1 + 448, 1952, 512);
    bias_combine<<<8, 64, 0, stream>>>(d1w, 0,   64,  t0b, d1b,     biasTot);
    bias_combine<<<8, 64, 0, stream>>>(d1w, 64,  128, t1b, biasTot, biasTot);
    bias_combine<<<8, 64, 0, stream>>>(d1w, 192, 256, t2b, biasTot, biasTot);
    bias_combine<<<8, 64, 0, stream>>>(d1w, 448, 512, t3b, biasTot, biasTot);

    auto G = [&](const bf16* A, int lda, const bf16* Wt, int ldw,
                 const float* bias, bf16* Cout, int ldc, int N, int K) {
        if (N >= 128) {
            int gy = N / 128, gx = Mc / 128;
            gemm_bf16<128><<<gx * gy, 256, 0, stream>>>(A, lda, Wt, ldw, bias,
                                                        Cout, ldc, gx, gy, K);
        } else {
            int gy = N / 64, gx = Mc / 128;
            gemm_bf16<64><<<gx * gy, 256, 0, stream>>>(A, lda, Wt, ldw, bias,
                                                       Cout, ldc, gx, gy, K);
        }
    };

    // ---- per-chunk pipeline ----
    for (int ch = 0; ch < nch; ++ch) {
        const int row0 = ch * Mc;

        copy3_kernel<<<(Mc + 255) / 256, 256, 0, stream>>>(points, row0, Mc, ptsb, 32);

        // level 0
        G(ptsb, 32, b0w1p, 32, b0b1, hbuf, 64, 64, 32);
        G(hbuf, 64, b0w2b, 64, b0b2, pc0, 64, 64, 64);
        adain_kernel<<<Mc / 4, 256, 0, stream>>>(pc0, 64, row0, mean2, scl2, feats + 0, 1952);
        // level 1
        G(pc0, 64, b1w1b, 64, b1b1, hbuf, 128, 128, 64);
        G(hbuf, 128, b1w2b, 128, b1b2, pc1, 128, 128, 128);
        adain_kernel<<<Mc / 4, 256, 0, stream>>>(pc1, 128, row0, mean3, scl3, feats + 64, 1952);
        // level 2
        G(pc1, 128, b2w1b, 128, b2b1, hbuf, 256, 256, 128);
        G(hbuf, 256, b2w2b, 256, b2b2, pc2, 256, 256, 256);
        adain_kernel<<<Mc / 4, 256, 0, stream>>>(pc2, 256, row0, mean4, scl4, feats + 192, 1952);
        // level 3
        G(pc2, 256, b3w1b, 256, b3b1, hbuf, 512, 512, 256);
        G(hbuf, 512, b3w2b, 512, b3b2, pc3, 512, 512, 512);
        adain_kernel<<<Mc / 4, 256, 0, stream>>>(pc3, 512, row0, mean5, scl5, feats + 448, 1952);

        // projections into feats cols 960..1919
        size_t tot;
        tot = (size_t)Mc * 64;
        proj_kernel<<<(tot + 255) / 256, 256, 0, stream>>>(points, pmat, feat2, 64, 112, 112, row0, Mc, feats + 960, 1952);
        tot = (size_t)Mc * 128;
        proj_kernel<<<(tot + 255) / 256, 256, 0, stream>>>(points, pmat, feat3, 128, 56, 56, row0, Mc, feats + 1024, 1952);
        tot = (size_t)Mc * 256;
        proj_kernel<<<(tot + 255) / 256, 256, 0, stream>>>(points, pmat, feat4, 256, 28, 28, row0, Mc, feats + 1152, 1952);
        tot = (size_t)Mc * 512;
        proj_kernel<<<(tot + 255) / 256, 256, 0, stream>>>(points, pmat, feat5, 512, 14, 14, row0, Mc, feats + 1408, 1952);

        // points cols 1920..1922 (cols 1923..1951 of Wd1 are zero -> garbage ok)
        copy3_kernel<<<(Mc + 255) / 256, 256, 0, stream>>>(points, row0, Mc, feats + 1920, 1952);

        // head
        G(feats, 1952, Wd1, 1952, biasTot, x1r, 512, 512, 1952);  // relu(x1)
        G(x1r, 512, d2wb, 512, d2b, x2, 256, 256, 512);           // relu(x2)
        G(x2, 256, d3wb, 256, d3b, x3, 128, 128, 256);            // relu(x3)
        final_kernel<<<(Mc + 255) / 256, 256, 0, stream>>>(x3, d4w, d4b, points,
                                                           row0, Mc, (float*)d_out);
    }
}

// Round 11
// 1777.008 us; speedup vs baseline: 3.3325x; 1.1947x over previous
//
#include <hip/hip_runtime.h>
#include <hip/hip_bf16.h>
#include <math.h>

#define BATCH   8
#define NPTS    8192
#define MTOT    (BATCH * NPTS)   // 65536 rows
#define EPSV    1e-8f

typedef __hip_bfloat16 bf16;
typedef __attribute__((ext_vector_type(8))) short short8;
typedef __attribute__((ext_vector_type(4))) float f32x4;

// ---------------------------------------------------------------------------
// Per-(b,c) image stats (fp32 input): mean + sqrt(var_ddof1 + eps)
__global__ __launch_bounds__(256) void stats_kernel(
    const float* __restrict__ feat, int HW,
    float* __restrict__ mean, float* __restrict__ scale)
{
    int bc = blockIdx.x;
    const float* p = feat + (size_t)bc * HW;
    float s = 0.f, s2 = 0.f;
    for (int i = threadIdx.x; i < HW; i += 256) {
        float v = p[i];
        s += v; s2 += v * v;
    }
    for (int off = 32; off; off >>= 1) {
        s  += __shfl_xor(s,  off);
        s2 += __shfl_xor(s2, off);
    }
    __shared__ float shs[4], shs2[4];
    int wave = threadIdx.x >> 6, lane = threadIdx.x & 63;
    if (lane == 0) { shs[wave] = s; shs2[wave] = s2; }
    __syncthreads();
    if (threadIdx.x == 0) {
        float S  = shs[0] + shs[1] + shs[2] + shs[3];
        float S2 = shs2[0] + shs2[1] + shs2[2] + shs2[3];
        float m = S / HW;
        float var = (S2 - HW * m * m) / (HW - 1);
        mean[bc]  = m;
        scale[bc] = sqrtf(var + EPSV);
    }
}

// ---------------------------------------------------------------------------
// Tiled fp32 fold: C[m,n] = sum_k A[m,k] * B[k,n]  (A=[512xK] lda, B=[KxN] ldb
// row-major NON-transposed, C bf16 ldc).  BM=BN=64, BK=16, 256 thr, 4x4/thr.
__global__ __launch_bounds__(256) void fold_kernel(
    const float* __restrict__ A, int lda,
    const float* __restrict__ B, int ldb,
    bf16* __restrict__ Cc, int ldc, int N, int K)
{
    __shared__ float As[16][65];
    __shared__ float Bs[16][65];
    const int tid = threadIdx.x;
    const int m0 = blockIdx.x * 64;
    const int bn = blockIdx.y * 64;
    const int tx = tid & 15, ty = tid >> 4;
    float acc[4][4] = {};

    for (int k0 = 0; k0 < K; k0 += 16) {
        #pragma unroll
        for (int i = tid; i < 64 * 16; i += 256) {
            int r = i >> 4, k = i & 15;
            As[k][r] = A[(size_t)(m0 + r) * lda + k0 + k];
        }
        #pragma unroll
        for (int i = tid; i < 64 * 16; i += 256) {
            int n = i & 63, k = i >> 6;
            Bs[k][n] = B[(size_t)(k0 + k) * ldb + bn + n];
        }
        __syncthreads();
        #pragma unroll
        for (int kk = 0; kk < 16; ++kk) {
            float a[4], b[4];
            #pragma unroll
            for (int i = 0; i < 4; ++i) a[i] = As[kk][ty * 4 + i];
            #pragma unroll
            for (int j = 0; j < 4; ++j) b[j] = Bs[kk][tx * 4 + j];
            #pragma unroll
            for (int i = 0; i < 4; ++i)
                #pragma unroll
                for (int j = 0; j < 4; ++j)
                    acc[i][j] += a[i] * b[j];
        }
        __syncthreads();
    }
    #pragma unroll
    for (int i = 0; i < 4; ++i)
        #pragma unroll
        for (int j = 0; j < 4; ++j)
            Cc[(size_t)(m0 + ty * 4 + i) * ldc + bn + tx * 4 + j] =
                __float2bfloat16(acc[i][j]);
}

// ---------------------------------------------------------------------------
// biasTot[n] = d1b[n] + sum_{k<960} d1w[n,k] * tcat[k], tcat = concat(t0b..t3b)
__global__ __launch_bounds__(64) void bias_all(
    const float* __restrict__ d1w, const float* __restrict__ d1b,
    const float* __restrict__ t0b, const float* __restrict__ t1b,
    const float* __restrict__ t2b, const float* __restrict__ t3b,
    float* __restrict__ out)
{
    int n = blockIdx.x;
    int lane = threadIdx.x;
    const float* row = d1w + (size_t)n * 1923;
    float s = 0.f;
    for (int k = lane; k < 960; k += 64) {
        float tv;
        if (k < 64)       tv = t0b[k];
        else if (k < 192) tv = t1b[k - 64];
        else if (k < 448) tv = t2b[k - 192];
        else              tv = t3b[k - 448];
        s += row[k] * tv;
    }
    for (int off = 32; off; off >>= 1) s += __shfl_xor(s, off);
    if (lane == 0) out[n] = d1b[n] + s;
}

// ---------------------------------------------------------------------------
// Batched fp32->bf16 strided weight conversion (src==null -> fill zero)
struct ConvDesc { const float* src; bf16* dst; int srcLd, dstLd, rows, cols; };
struct ConvArgs { ConvDesc d[20]; int n; };

__global__ __launch_bounds__(256) void conv_batch(ConvArgs a)
{
    int di = blockIdx.y;
    if (di >= a.n) return;
    ConvDesc d = a.d[di];
    int total = d.rows * d.cols;
    for (int idx = blockIdx.x * 256 + threadIdx.x; idx < total;
         idx += gridDim.x * 256) {
        int r = idx / d.cols, c = idx % d.cols;
        float v = d.src ? d.src[(size_t)r * d.srcLd + c] : 0.f;
        d.dst[(size_t)r * d.dstLd + c] = __float2bfloat16(v);
    }
}

// ---------------------------------------------------------------------------
// bf16 MFMA GEMM: C[M,N] = relu(A[M,K] @ W[N,K]^T + bias), bf16 out.
// BM=128, BN template (64/128), BK=32, 256 threads (4 waves).
template<int BN>
__global__ __launch_bounds__(256) void gemm_bf16(
    const bf16* __restrict__ A, int lda,
    const bf16* __restrict__ W, int ldw,
    const float* __restrict__ bias,
    bf16* __restrict__ C, int ldc,
    int gx, int gy, int K)
{
    constexpr int LDK = 40;  // 32 + 8 pad (2-way LDS aliasing only)
    __shared__ __align__(16) bf16 As[128 * LDK];
    __shared__ __align__(16) bf16 Bs[BN * LDK];

    int nblk = gx * gy;
    int bid = blockIdx.x;
    if ((nblk & 7) == 0) {                 // XCD-chunked swizzle (T1)
        int cpx = nblk >> 3;
        bid = (bid & 7) * cpx + (bid >> 3);
    }
    const int bm = (bid / gy) * 128;
    const int bn = (bid % gy) * BN;

    const int tid = threadIdx.x;
    const int wave = tid >> 6, lane = tid & 63;
    constexpr int FM = (BN == 128) ? 4 : 2;
    constexpr int FN = 4;
    const int wm = (BN == 128) ? (wave >> 1) * 64 : wave * 32;
    const int wn = (BN == 128) ? (wave & 1) * 64 : 0;

    f32x4 acc[FM][FN] = {};

    const int arow = tid >> 1;
    const int akh  = (tid & 1) * 16;
    const int brow = (BN == 128) ? (tid >> 1) : (tid >> 2);
    const int bkh  = (BN == 128) ? (tid & 1) * 16 : (tid & 3) * 8;

    const int fr = lane & 15, kq = lane >> 4;

    for (int k0 = 0; k0 < K; k0 += 32) {
        {   // stage A: 16 bf16 (32B) per thread
            const uint4* src = reinterpret_cast<const uint4*>(
                A + (size_t)(bm + arow) * lda + k0 + akh);
            uint4 v0 = src[0], v1 = src[1];
            uint4* dst = reinterpret_cast<uint4*>(&As[arow * LDK + akh]);
            dst[0] = v0; dst[1] = v1;
        }
        if (BN == 128) {
            const uint4* src = reinterpret_cast<const uint4*>(
                W + (size_t)(bn + brow) * ldw + k0 + bkh);
            uint4 v0 = src[0], v1 = src[1];
            uint4* dst = reinterpret_cast<uint4*>(&Bs[brow * LDK + bkh]);
            dst[0] = v0; dst[1] = v1;
        } else {
            const uint4* src = reinterpret_cast<const uint4*>(
                W + (size_t)(bn + brow) * ldw + k0 + bkh);
            uint4 v0 = src[0];
            uint4* dst = reinterpret_cast<uint4*>(&Bs[brow * LDK + bkh]);
            dst[0] = v0;
        }
        __syncthreads();

        short8 a[FM], b[FN];
        #pragma unroll
        for (int i = 0; i < FM; ++i)
            a[i] = *reinterpret_cast<const short8*>(
                &As[(wm + i * 16 + fr) * LDK + kq * 8]);
        #pragma unroll
        for (int j = 0; j < FN; ++j)
            b[j] = *reinterpret_cast<const short8*>(
                &Bs[(wn + j * 16 + fr) * LDK + kq * 8]);
        #pragma unroll
        for (int i = 0; i < FM; ++i)
            #pragma unroll
            for (int j = 0; j < FN; ++j)
                acc[i][j] = __builtin_amdgcn_mfma_f32_16x16x32_bf16(
                    a[i], b[j], acc[i][j], 0, 0, 0);
        __syncthreads();
    }

    // epilogue: bias + relu -> bf16
    const int rq = lane >> 4;
    #pragma unroll
    for (int j = 0; j < FN; ++j) {
        int n = bn + wn + j * 16 + fr;
        float bv = bias[n];
        #pragma unroll
        for (int i = 0; i < FM; ++i) {
            int mbase = bm + wm + i * 16 + rq * 4;
            #pragma unroll
            for (int q = 0; q < 4; ++q) {
                float v = acc[i][j][q] + bv;
                v = fmaxf(v, 0.f);
                C[(size_t)(mbase + q) * ldc + n] = __float2bfloat16(v);
            }
        }
    }
}

// ---------------------------------------------------------------------------
// AdaIN modulate: bf16 in, bf16 out (strided into feats)
__global__ __launch_bounds__(256) void adain_kernel(
    const bf16* __restrict__ pc, int C, int row0,
    const float* __restrict__ img_mean, const float* __restrict__ img_scale,
    bf16* __restrict__ out, int ldout)
{
    int wave = threadIdx.x >> 6;
    int lane = threadIdx.x & 63;
    size_t row = (size_t)blockIdx.x * 4 + wave;
    int b = (int)((row0 + row) / NPTS);
    const bf16* x = pc + row * C;
    int nper = C >> 6;
    float vals[8];
    float s = 0.f, s2 = 0.f;
    for (int i = 0; i < nper; ++i) {
        float v = __bfloat162float(x[lane + (i << 6)]);
        vals[i] = v; s += v; s2 += v * v;
    }
    for (int off = 32; off; off >>= 1) {
        s  += __shfl_xor(s,  off);
        s2 += __shfl_xor(s2, off);
    }
    float mean = s / C;
    float var = (s2 - C * mean * mean) / (C - 1);
    float inv = 1.f / sqrtf(var + EPSV);
    const float* im = img_mean + (size_t)b * C;
    const float* is_ = img_scale + (size_t)b * C;
    bf16* o = out + row * ldout;
    for (int i = 0; i < nper; ++i) {
        int c = lane + (i << 6);
        o[c] = __float2bfloat16(((vals[i] - mean) * inv + im[c]) * is_[c]);
    }
}

// ---------------------------------------------------------------------------
// Projection + bilinear gather -> bf16 strided into feats
__global__ __launch_bounds__(256) void proj_kernel(
    const float* __restrict__ points, const float* __restrict__ pm,
    const float* __restrict__ feat, int C, int H, int W, int row0, int Mc,
    bf16* __restrict__ out, int ldout)
{
    size_t idx = (size_t)blockIdx.x * 256 + threadIdx.x;
    size_t total = (size_t)Mc * C;
    if (idx >= total) return;
    int c = (int)(idx % C);
    size_t m = idx / C;
    size_t gm = (size_t)row0 + m;
    int b = (int)(gm / NPTS);
    const float* p = points + gm * 3;
    const float* P = pm + (size_t)b * 16;
    float px = p[0], py = p[1], pz = p[2];
    float c0 = P[0]  * px + P[1]  * py + P[2]  * pz + P[3];
    float c1 = P[4]  * px + P[5]  * py + P[6]  * pz + P[7];
    float c3 = P[12] * px + P[13] * py + P[14] * pz + P[15];
    float x = (c0 / c3 + 1.f) * 0.5f;
    float y = 1.f - (c1 / c3 + 1.f) * 0.5f;
    float x0 = fminf(fmaxf(x * W, 0.f), (float)(W - 1));
    float y0 = fminf(fmaxf(y * H, 0.f), (float)(H - 1));
    float x1f = floorf(x0), x2f = ceilf(x0);
    float y1f = floorf(y0), y2f = ceilf(y0);
    int xi1 = (int)x1f, xi2 = (int)x2f, yi1 = (int)y1f, yi2 = (int)y2f;
    const float* fb = feat + ((size_t)b * C + c) * (size_t)(H * W);
    float Q11 = fb[yi1 * W + xi1];
    float Q12 = fb[yi2 * W + xi1];
    float Q21 = fb[yi1 * W + xi2];
    float Q22 = fb[yi2 * W + xi2];
    float wx2 = x2f - x0, wx1 = x0 - x1f;
    float wy2 = y2f - y0, wy1 = y0 - y1f;
    float r = wx2 * wy2 * Q11 + wx1 * wy2 * Q21
            + wx2 * wy1 * Q12 + wx1 * wy1 * Q22;
    out[m * ldout + c] = __float2bfloat16(r);
}

// ---------------------------------------------------------------------------
// copy 3 fp32 point coords per row into a bf16 buffer (cols 0..2)
__global__ __launch_bounds__(256) void copy3_kernel(
    const float* __restrict__ pts, int row0, int Mc,
    bf16* __restrict__ dst, int dld)
{
    int m = blockIdx.x * 256 + threadIdx.x;
    if (m >= Mc) return;
    const float* p = pts + (size_t)(row0 + m) * 3;
    bf16* d = dst + (size_t)m * dld;
    d[0] = __float2bfloat16(p[0]);
    d[1] = __float2bfloat16(p[1]);
    d[2] = __float2bfloat16(p[2]);
}

// ---------------------------------------------------------------------------
// out[row0+m,:] = x3[m,:] @ d4w^T + d4b + points[row0+m,:]   (x3 pre-relu'd)
__global__ __launch_bounds__(256) void final_kernel(
    const bf16* __restrict__ x3, const float* __restrict__ w,
    const float* __restrict__ bb, const float* __restrict__ points,
    int row0, int Mc, float* __restrict__ out)
{
    size_t m = (size_t)blockIdx.x * 256 + threadIdx.x;
    if (m >= (size_t)Mc) return;
    size_t gm = (size_t)row0 + m;
    float a0 = bb[0], a1 = bb[1], a2 = bb[2];
    const bf16* x = x3 + m * 128;
    #pragma unroll 4
    for (int k = 0; k < 128; ++k) {
        float v = __bfloat162float(x[k]);
        a0 += v * w[k];
        a1 += v * w[128 + k];
        a2 += v * w[256 + k];
    }
    out[gm * 3 + 0] = a0 + points[gm * 3 + 0];
    out[gm * 3 + 1] = a1 + points[gm * 3 + 1];
    out[gm * 3 + 2] = a2 + points[gm * 3 + 2];
}

// ---------------------------------------------------------------------------
extern "C" void kernel_launch(void* const* d_in, const int* in_sizes, int n_in,
                              void* d_out, int out_size, void* d_ws, size_t ws_size,
                              hipStream_t stream)
{
    const float* points = (const float*)d_in[0];
    const float* feat2  = (const float*)d_in[1];
    const float* feat3  = (const float*)d_in[2];
    const float* feat4  = (const float*)d_in[3];
    const float* feat5  = (const float*)d_in[4];
    const float* pmat   = (const float*)d_in[5];
    const float* b0w1 = (const float*)d_in[6];  const float* b0b1 = (const float*)d_in[7];
    const float* b0w2 = (const float*)d_in[8];  const float* b0b2 = (const float*)d_in[9];
    const float* t0w  = (const float*)d_in[10]; const float* t0b  = (const float*)d_in[11];
    const float* b1w1 = (const float*)d_in[12]; const float* b1b1 = (const float*)d_in[13];
    const float* b1w2 = (const float*)d_in[14]; const float* b1b2 = (const float*)d_in[15];
    const float* t1w  = (const float*)d_in[16]; const float* t1b  = (const float*)d_in[17];
    const float* b2w1 = (const float*)d_in[18]; const float* b2b1 = (const float*)d_in[19];
    const float* b2w2 = (const float*)d_in[20]; const float* b2b2 = (const float*)d_in[21];
    const float* t2w  = (const float*)d_in[22]; const float* t2b  = (const float*)d_in[23];
    const float* b3w1 = (const float*)d_in[24]; const float* b3b1 = (const float*)d_in[25];
    const float* b3w2 = (const float*)d_in[26]; const float* b3b2 = (const float*)d_in[27];
    const float* t3w  = (const float*)d_in[28]; const float* t3b  = (const float*)d_in[29];
    const float* d1w  = (const float*)d_in[30]; const float* d1b  = (const float*)d_in[31];
    const float* d2w  = (const float*)d_in[32]; const float* d2b  = (const float*)d_in[33];
    const float* d3w  = (const float*)d_in[34]; const float* d3b  = (const float*)d_in[35];
    const float* d4w  = (const float*)d_in[36]; const float* d4b  = (const float*)d_in[37];

    // ---- fp32 shared region ----
    float* wsf = (float*)d_ws;
    float* biasTot = wsf;                  // 512
    float* smean   = wsf + 512;            // 7680
    float* sscale  = smean + 7680;         // 7680
    const size_t F32_FLOATS = 512 + 2 * 7680;   // 15872
    float* mean2 = smean, *mean3 = smean + 512, *mean4 = smean + 1536, *mean5 = smean + 3584;
    float* scl2 = sscale, *scl3 = sscale + 512, *scl4 = sscale + 1536, *scl5 = sscale + 3584;

    // ---- bf16 shared region: packed weights ----
    bf16* wb = (bf16*)(wsf + F32_FLOATS);
    bf16* Wd1   = wb;                       // 512 x 1952
    bf16* b0w1p = Wd1   + (size_t)512 * 1952;  // 64 x 32 (cols 3..31 zero)
    bf16* b0w2b = b0w1p + 64 * 32;          // 64 x 64
    bf16* b1w1b = b0w2b + 64 * 64;          // 128 x 64
    bf16* b1w2b = b1w1b + 128 * 64;         // 128 x 128
    bf16* b2w1b = b1w2b + 128 * 128;        // 256 x 128
    bf16* b2w2b = b2w1b + 256 * 128;        // 256 x 256
    bf16* b3w1b = b2w2b + 256 * 256;        // 512 x 256
    bf16* b3w2b = b3w1b + 512 * 256;        // 512 x 512
    bf16* d2wb  = b3w2b + (size_t)512 * 512; // 256 x 512
    bf16* d3wb  = d2wb  + (size_t)256 * 512; // 128 x 256
    const size_t SHARED_BF = (size_t)512 * 1952 + 64 * 32 + 64 * 64 + 128 * 64
        + 128 * 128 + 256 * 128 + 256 * 256 + (size_t)512 * 256
        + (size_t)512 * 512 + (size_t)256 * 512 + 128 * 256;   // 1,685,504

    const size_t SHARED_BYTES = F32_FLOATS * 4 + SHARED_BF * 2;

    // ---- chunking: per-row bf16 = 32+512+64+128+256+512+1952+512+256+128 = 4352
    const size_t PER_ROW_BYTES = 4352 * 2;
    size_t avail = (ws_size > SHARED_BYTES) ? ws_size - SHARED_BYTES : 0;
    int nch = 1;
    while (nch < 512 && (size_t)(MTOT / nch) * PER_ROW_BYTES > avail) nch <<= 1;
    const int Mc = MTOT / nch;

    bf16* cb = wb + SHARED_BF;
    bf16* ptsb  = cb;                          // Mc x 32
    bf16* hbuf  = ptsb  + (size_t)Mc * 32;     // Mc x <=512
    bf16* pc0   = hbuf  + (size_t)Mc * 512;    // Mc x 64
    bf16* pc1   = pc0   + (size_t)Mc * 64;     // Mc x 128
    bf16* pc2   = pc1   + (size_t)Mc * 128;    // Mc x 256
    bf16* pc3   = pc2   + (size_t)Mc * 256;    // Mc x 512
    bf16* feats = pc3   + (size_t)Mc * 512;    // Mc x 1952
    bf16* x1r   = feats + (size_t)Mc * 1952;   // Mc x 512
    bf16* x2    = x1r   + (size_t)Mc * 512;    // Mc x 256
    bf16* x3    = x2    + (size_t)Mc * 256;    // Mc x 128

    // ---- prep: stats ----
    stats_kernel<<<8 * 64,  256, 0, stream>>>(feat2, 112 * 112, mean2, scl2);
    stats_kernel<<<8 * 128, 256, 0, stream>>>(feat3, 56 * 56,  mean3, scl3);
    stats_kernel<<<8 * 256, 256, 0, stream>>>(feat4, 28 * 28,  mean4, scl4);
    stats_kernel<<<8 * 512, 256, 0, stream>>>(feat5, 14 * 14,  mean5, scl5);

    // ---- prep: weight conversions (one batched launch) ----
    ConvArgs ca;
    int nd = 0;
    auto addc = [&](const float* s, bf16* d, int sld, int dld, int r, int c) {
        ca.d[nd++] = ConvDesc{ s, d, sld, dld, r, c };
    };
    addc(b0w1, b0w1p, 3, 32, 64, 3);
    addc(nullptr, b0w1p + 3, 0, 32, 64, 29);        // zero pad cols 3..31
    addc(b0w2, b0w2b, 64, 64, 64, 64);
    addc(b1w1, b1w1b, 64, 64, 128, 64);
    addc(b1w2, b1w2b, 128, 128, 128, 128);
    addc(b2w1, b2w1b, 128, 128, 256, 128);
    addc(b2w2, b2w2b, 256, 256, 256, 256);
    addc(b3w1, b3w1b, 256, 256, 512, 256);
    addc(b3w2, b3w2b, 512, 512, 512, 512);
    addc(d2w, d2wb, 512, 512, 256, 512);
    addc(d3w, d3wb, 256, 256, 128, 256);
    addc(d1w + 960,  Wd1 + 960,  1923, 1952, 512, 64);   // proj2 chunk
    addc(d1w + 1024, Wd1 + 1024, 1923, 1952, 512, 128);  // proj3
    addc(d1w + 1152, Wd1 + 1152, 1923, 1952, 512, 256);  // proj4
    addc(d1w + 1408, Wd1 + 1408, 1923, 1952, 512, 512);  // proj5
    addc(d1w + 1920, Wd1 + 1920, 1923, 1952, 512, 3);    // points cols
    addc(nullptr,    Wd1 + 1923, 0,    1952, 512, 29);   // zero pad 1923..1951
    ca.n = nd;
    conv_batch<<<dim3(64, nd), 256, 0, stream>>>(ca);

    // ---- prep: folded transform weights into Wd1 cols 0..959 (tiled fp32) ----
    fold_kernel<<<dim3(8, 1), 256, 0, stream>>>(d1w + 0,   1923, t0w, 64,  Wd1 + 0,   1952, 64,  64);
    fold_kernel<<<dim3(8, 2), 256, 0, stream>>>(d1w + 64,  1923, t1w, 128, Wd1 + 64,  1952, 128, 128);
    fold_kernel<<<dim3(8, 4), 256, 0, stream>>>(d1w + 192, 1923, t2w, 256, Wd1 + 192, 1952, 256, 256);
    fold_kernel<<<dim3(8, 8), 256, 0, stream>>>(d1w + 448, 1923, t3w, 512, Wd1 + 448, 1952, 512, 512);
    bias_all<<<512, 64, 0, stream>>>(d1w, d1b, t0b, t1b, t2b, t3b, biasTot);

    auto G = [&](const bf16* A, int lda, const bf16* Wt, int ldw,
                 const float* bias, bf16* Cout, int ldc, int N, int K) {
        if (N >= 128) {
            int gy = N / 128, gx = Mc / 128;
            gemm_bf16<128><<<gx * gy, 256, 0, stream>>>(A, lda, Wt, ldw, bias,
                                                        Cout, ldc, gx, gy, K);
        } else {
            int gy = N / 64, gx = Mc / 128;
            gemm_bf16<64><<<gx * gy, 256, 0, stream>>>(A, lda, Wt, ldw, bias,
                                                       Cout, ldc, gx, gy, K);
        }
    };

    // ---- per-chunk pipeline ----
    for (int ch = 0; ch < nch; ++ch) {
        const int row0 = ch * Mc;

        copy3_kernel<<<(Mc + 255) / 256, 256, 0, stream>>>(points, row0, Mc, ptsb, 32);

        // level 0
        G(ptsb, 32, b0w1p, 32, b0b1, hbuf, 64, 64, 32);
        G(hbuf, 64, b0w2b, 64, b0b2, pc0, 64, 64, 64);
        adain_kernel<<<Mc / 4, 256, 0, stream>>>(pc0, 64, row0, mean2, scl2, feats + 0, 1952);
        // level 1
        G(pc0, 64, b1w1b, 64, b1b1, hbuf, 128, 128, 64);
        G(hbuf, 128, b1w2b, 128, b1b2, pc1, 128, 128, 128);
        adain_kernel<<<Mc / 4, 256, 0, stream>>>(pc1, 128, row0, mean3, scl3, feats + 64, 1952);
        // level 2
        G(pc1, 128, b2w1b, 128, b2b1, hbuf, 256, 256, 128);
        G(hbuf, 256, b2w2b, 256, b2b2, pc2, 256, 256, 256);
        adain_kernel<<<Mc / 4, 256, 0, stream>>>(pc2, 256, row0, mean4, scl4, feats + 192, 1952);
        // level 3
        G(pc2, 256, b3w1b, 256, b3b1, hbuf, 512, 512, 256);
        G(hbuf, 512, b3w2b, 512, b3b2, pc3, 512, 512, 512);
        adain_kernel<<<Mc / 4, 256, 0, stream>>>(pc3, 512, row0, mean5, scl5, feats + 448, 1952);

        // projections into feats cols 960..1919
        size_t tot;
        tot = (size_t)Mc * 64;
        proj_kernel<<<(tot + 255) / 256, 256, 0, stream>>>(points, pmat, feat2, 64, 112, 112, row0, Mc, feats + 960, 1952);
        tot = (size_t)Mc * 128;
        proj_kernel<<<(tot + 255) / 256, 256, 0, stream>>>(points, pmat, feat3, 128, 56, 56, row0, Mc, feats + 1024, 1952);
        tot = (size_t)Mc * 256;
        proj_kernel<<<(tot + 255) / 256, 256, 0, stream>>>(points, pmat, feat4, 256, 28, 28, row0, Mc, feats + 1152, 1952);
        tot = (size_t)Mc * 512;
        proj_kernel<<<(tot + 255) / 256, 256, 0, stream>>>(points, pmat, feat5, 512, 14, 14, row0, Mc, feats + 1408, 1952);

        // points cols 1920..1922 (cols 1923..1951 of Wd1 are zero -> garbage ok)
        copy3_kernel<<<(Mc + 255) / 256, 256, 0, stream>>>(points, row0, Mc, feats + 1920, 1952);

        // head
        G(feats, 1952, Wd1, 1952, biasTot, x1r, 512, 512, 1952);  // relu(x1)
        G(x1r, 512, d2wb, 512, d2b, x2, 256, 256, 512);           // relu(x2)
        G(x2, 256, d3wb, 256, d3b, x3, 128, 128, 256);            // relu(x3)
        final_kernel<<<(Mc + 255) / 256, 256, 0, stream>>>(x3, d4w, d4b, points,
                                                           row0, Mc, (float*)d_out);
    }
}

// Round 12
// 1625.601 us; speedup vs baseline: 3.6429x; 1.0931x over previous
//
#include <hip/hip_runtime.h>
#include <hip/hip_bf16.h>
#include <math.h>

#define BATCH   8
#define NPTS    8192
#define MTOT    (BATCH * NPTS)   // 65536 rows
#define EPSV    1e-8f

typedef __hip_bfloat16 bf16;
typedef __attribute__((ext_vector_type(8))) short short8;
typedef __attribute__((ext_vector_type(4))) float f32x4;

// ---------------------------------------------------------------------------
// Per-(b,c) image stats (fp32 input): mean + sqrt(var_ddof1 + eps)
__global__ __launch_bounds__(256) void stats_kernel(
    const float* __restrict__ feat, int HW,
    float* __restrict__ mean, float* __restrict__ scale)
{
    int bc = blockIdx.x;
    const float* p = feat + (size_t)bc * HW;
    float s = 0.f, s2 = 0.f;
    for (int i = threadIdx.x; i < HW; i += 256) {
        float v = p[i];
        s += v; s2 += v * v;
    }
    for (int off = 32; off; off >>= 1) {
        s  += __shfl_xor(s,  off);
        s2 += __shfl_xor(s2, off);
    }
    __shared__ float shs[4], shs2[4];
    int wave = threadIdx.x >> 6, lane = threadIdx.x & 63;
    if (lane == 0) { shs[wave] = s; shs2[wave] = s2; }
    __syncthreads();
    if (threadIdx.x == 0) {
        float S  = shs[0] + shs[1] + shs[2] + shs[3];
        float S2 = shs2[0] + shs2[1] + shs2[2] + shs2[3];
        float m = S / HW;
        float var = (S2 - HW * m * m) / (HW - 1);
        mean[bc]  = m;
        scale[bc] = sqrtf(var + EPSV);
    }
}

// ---------------------------------------------------------------------------
// Split-K fused fold: all 4 transforms in ONE launch (680 blocks).
// Block computes a 64x64 tile of (d1w_chunk @ t_w) for a 64-wide K slice and
// stores it (plain stores, no atomics) into foldtmp[kslice][512][960].
struct FoldDesc { int aoff; const float* B; int C; int nbase; int blkBase; int nt; int kt; };
struct FoldArgs { FoldDesc d[4]; };

__global__ __launch_bounds__(256) void fold_splitk(
    const float* __restrict__ d1w, float* __restrict__ foldtmp, FoldArgs args)
{
    int bid = blockIdx.x;
    int f = (bid >= 168) ? 3 : (bid >= 40) ? 2 : (bid >= 8) ? 1 : 0;
    FoldDesc d = args.d[f];
    int local = bid - d.blkBase;
    int ks  = local % d.kt;
    int ntI = (local / d.kt) % d.nt;
    int mt  = local / (d.kt * d.nt);
    const int m0 = mt * 64, n0 = ntI * 64, kbase = ks * 64;

    const float* A = d1w + d.aoff;       // lda = 1923
    const float* B = d.B;                // ldb = d.C

    __shared__ float As[16][65];
    __shared__ float Bs[16][65];
    const int tid = threadIdx.x;
    const int tx = tid & 15, ty = tid >> 4;
    float acc[4][4] = {};

    for (int k0 = kbase; k0 < kbase + 64; k0 += 16) {
        #pragma unroll
        for (int i = tid; i < 64 * 16; i += 256) {
            int r = i >> 4, k = i & 15;
            As[k][r] = A[(size_t)(m0 + r) * 1923 + k0 + k];
        }
        #pragma unroll
        for (int i = tid; i < 64 * 16; i += 256) {
            int n = i & 63, k = i >> 6;
            Bs[k][n] = B[(size_t)(k0 + k) * d.C + n0 + n];
        }
        __syncthreads();
        #pragma unroll
        for (int kk = 0; kk < 16; ++kk) {
            float a[4], b[4];
            #pragma unroll
            for (int i = 0; i < 4; ++i) a[i] = As[kk][ty * 4 + i];
            #pragma unroll
            for (int j = 0; j < 4; ++j) b[j] = Bs[kk][tx * 4 + j];
            #pragma unroll
            for (int i = 0; i < 4; ++i)
                #pragma unroll
                for (int j = 0; j < 4; ++j)
                    acc[i][j] += a[i] * b[j];
        }
        __syncthreads();
    }
    float* dst = foldtmp + ((size_t)ks * 512) * 960;
    #pragma unroll
    for (int i = 0; i < 4; ++i)
        #pragma unroll
        for (int j = 0; j < 4; ++j)
            dst[(size_t)(m0 + ty * 4 + i) * 960 + d.nbase + n0 + tx * 4 + j] =
                acc[i][j];
}

// Sum the kt partial slices per region, emit bf16 into Wd1 (ld 1952).
__global__ __launch_bounds__(256) void fold_convert(
    const float* __restrict__ foldtmp, bf16* __restrict__ Wd1)
{
    int idx = blockIdx.x * 256 + threadIdx.x;
    if (idx >= 512 * 960) return;
    int m = idx / 960, n = idx % 960;
    int kt = (n < 64) ? 1 : (n < 192) ? 2 : (n < 448) ? 4 : 8;
    float s = 0.f;
    for (int k = 0; k < kt; ++k)
        s += foldtmp[((size_t)k * 512 + m) * 960 + n];
    Wd1[(size_t)m * 1952 + n] = __float2bfloat16(s);
}

// ---------------------------------------------------------------------------
// biasTot[n] = d1b[n] + sum_{k<960} d1w[n,k] * tcat[k], tcat = concat(t0b..t3b)
__global__ __launch_bounds__(64) void bias_all(
    const float* __restrict__ d1w, const float* __restrict__ d1b,
    const float* __restrict__ t0b, const float* __restrict__ t1b,
    const float* __restrict__ t2b, const float* __restrict__ t3b,
    float* __restrict__ out)
{
    int n = blockIdx.x;
    int lane = threadIdx.x;
    const float* row = d1w + (size_t)n * 1923;
    float s = 0.f;
    for (int k = lane; k < 960; k += 64) {
        float tv;
        if (k < 64)       tv = t0b[k];
        else if (k < 192) tv = t1b[k - 64];
        else if (k < 448) tv = t2b[k - 192];
        else              tv = t3b[k - 448];
        s += row[k] * tv;
    }
    for (int off = 32; off; off >>= 1) s += __shfl_xor(s, off);
    if (lane == 0) out[n] = d1b[n] + s;
}

// ---------------------------------------------------------------------------
// Batched fp32->bf16 strided weight conversion (src==null -> fill zero)
struct ConvDesc { const float* src; bf16* dst; int srcLd, dstLd, rows, cols; };
struct ConvArgs { ConvDesc d[20]; int n; };

__global__ __launch_bounds__(256) void conv_batch(ConvArgs a)
{
    int di = blockIdx.y;
    if (di >= a.n) return;
    ConvDesc d = a.d[di];
    int total = d.rows * d.cols;
    for (int idx = blockIdx.x * 256 + threadIdx.x; idx < total;
         idx += gridDim.x * 256) {
        int r = idx / d.cols, c = idx % d.cols;
        float v = d.src ? d.src[(size_t)r * d.srcLd + c] : 0.f;
        d.dst[(size_t)r * d.dstLd + c] = __float2bfloat16(v);
    }
}

// ---------------------------------------------------------------------------
// bf16 MFMA GEMM: C[M,N] = relu(A[M,K] @ W[N,K]^T + bias), bf16 out.
// BM=128, BN template (64/128), BK=32, 256 threads (4 waves).
template<int BN>
__global__ __launch_bounds__(256) void gemm_bf16(
    const bf16* __restrict__ A, int lda,
    const bf16* __restrict__ W, int ldw,
    const float* __restrict__ bias,
    bf16* __restrict__ C, int ldc,
    int gx, int gy, int K)
{
    constexpr int LDK = 40;  // 32 + 8 pad (2-way LDS aliasing only)
    __shared__ __align__(16) bf16 As[128 * LDK];
    __shared__ __align__(16) bf16 Bs[BN * LDK];

    int nblk = gx * gy;
    int bid = blockIdx.x;
    if ((nblk & 7) == 0) {                 // XCD-chunked swizzle (T1)
        int cpx = nblk >> 3;
        bid = (bid & 7) * cpx + (bid >> 3);
    }
    const int bm = (bid / gy) * 128;
    const int bn = (bid % gy) * BN;

    const int tid = threadIdx.x;
    const int wave = tid >> 6, lane = tid & 63;
    constexpr int FM = (BN == 128) ? 4 : 2;
    constexpr int FN = 4;
    const int wm = (BN == 128) ? (wave >> 1) * 64 : wave * 32;
    const int wn = (BN == 128) ? (wave & 1) * 64 : 0;

    f32x4 acc[FM][FN] = {};

    const int arow = tid >> 1;
    const int akh  = (tid & 1) * 16;
    const int brow = (BN == 128) ? (tid >> 1) : (tid >> 2);
    const int bkh  = (BN == 128) ? (tid & 1) * 16 : (tid & 3) * 8;

    const int fr = lane & 15, kq = lane >> 4;

    for (int k0 = 0; k0 < K; k0 += 32) {
        {   // stage A: 16 bf16 (32B) per thread
            const uint4* src = reinterpret_cast<const uint4*>(
                A + (size_t)(bm + arow) * lda + k0 + akh);
            uint4 v0 = src[0], v1 = src[1];
            uint4* dst = reinterpret_cast<uint4*>(&As[arow * LDK + akh]);
            dst[0] = v0; dst[1] = v1;
        }
        if (BN == 128) {
            const uint4* src = reinterpret_cast<const uint4*>(
                W + (size_t)(bn + brow) * ldw + k0 + bkh);
            uint4 v0 = src[0], v1 = src[1];
            uint4* dst = reinterpret_cast<uint4*>(&Bs[brow * LDK + bkh]);
            dst[0] = v0; dst[1] = v1;
        } else {
            const uint4* src = reinterpret_cast<const uint4*>(
                W + (size_t)(bn + brow) * ldw + k0 + bkh);
            uint4 v0 = src[0];
            uint4* dst = reinterpret_cast<uint4*>(&Bs[brow * LDK + bkh]);
            dst[0] = v0;
        }
        __syncthreads();

        short8 a[FM], b[FN];
        #pragma unroll
        for (int i = 0; i < FM; ++i)
            a[i] = *reinterpret_cast<const short8*>(
                &As[(wm + i * 16 + fr) * LDK + kq * 8]);
        #pragma unroll
        for (int j = 0; j < FN; ++j)
            b[j] = *reinterpret_cast<const short8*>(
                &Bs[(wn + j * 16 + fr) * LDK + kq * 8]);
        #pragma unroll
        for (int i = 0; i < FM; ++i)
            #pragma unroll
            for (int j = 0; j < FN; ++j)
                acc[i][j] = __builtin_amdgcn_mfma_f32_16x16x32_bf16(
                    a[i], b[j], acc[i][j], 0, 0, 0);
        __syncthreads();
    }

    // epilogue: bias + relu -> bf16
    const int rq = lane >> 4;
    #pragma unroll
    for (int j = 0; j < FN; ++j) {
        int n = bn + wn + j * 16 + fr;
        float bv = bias[n];
        #pragma unroll
        for (int i = 0; i < FM; ++i) {
            int mbase = bm + wm + i * 16 + rq * 4;
            #pragma unroll
            for (int q = 0; q < 4; ++q) {
                float v = acc[i][j][q] + bv;
                v = fmaxf(v, 0.f);
                C[(size_t)(mbase + q) * ldc + n] = __float2bfloat16(v);
            }
        }
    }
}

// ---------------------------------------------------------------------------
// AdaIN modulate: bf16 in, bf16 out (strided into feats)
__global__ __launch_bounds__(256) void adain_kernel(
    const bf16* __restrict__ pc, int C, int row0,
    const float* __restrict__ img_mean, const float* __restrict__ img_scale,
    bf16* __restrict__ out, int ldout)
{
    int wave = threadIdx.x >> 6;
    int lane = threadIdx.x & 63;
    size_t row = (size_t)blockIdx.x * 4 + wave;
    int b = (int)((row0 + row) / NPTS);
    const bf16* x = pc + row * C;
    int nper = C >> 6;
    float vals[8];
    float s = 0.f, s2 = 0.f;
    for (int i = 0; i < nper; ++i) {
        float v = __bfloat162float(x[lane + (i << 6)]);
        vals[i] = v; s += v; s2 += v * v;
    }
    for (int off = 32; off; off >>= 1) {
        s  += __shfl_xor(s,  off);
        s2 += __shfl_xor(s2, off);
    }
    float mean = s / C;
    float var = (s2 - C * mean * mean) / (C - 1);
    float inv = 1.f / sqrtf(var + EPSV);
    const float* im = img_mean + (size_t)b * C;
    const float* is_ = img_scale + (size_t)b * C;
    bf16* o = out + row * ldout;
    for (int i = 0; i < nper; ++i) {
        int c = lane + (i << 6);
        o[c] = __float2bfloat16(((vals[i] - mean) * inv + im[c]) * is_[c]);
    }
}

// ---------------------------------------------------------------------------
// Projection + bilinear gather -> bf16 strided into feats
__global__ __launch_bounds__(256) void proj_kernel(
    const float* __restrict__ points, const float* __restrict__ pm,
    const float* __restrict__ feat, int C, int H, int W, int row0, int Mc,
    bf16* __restrict__ out, int ldout)
{
    size_t idx = (size_t)blockIdx.x * 256 + threadIdx.x;
    size_t total = (size_t)Mc * C;
    if (idx >= total) return;
    int c = (int)(idx % C);
    size_t m = idx / C;
    size_t gm = (size_t)row0 + m;
    int b = (int)(gm / NPTS);
    const float* p = points + gm * 3;
    const float* P = pm + (size_t)b * 16;
    float px = p[0], py = p[1], pz = p[2];
    float c0 = P[0]  * px + P[1]  * py + P[2]  * pz + P[3];
    float c1 = P[4]  * px + P[5]  * py + P[6]  * pz + P[7];
    float c3 = P[12] * px + P[13] * py + P[14] * pz + P[15];
    float x = (c0 / c3 + 1.f) * 0.5f;
    float y = 1.f - (c1 / c3 + 1.f) * 0.5f;
    float x0 = fminf(fmaxf(x * W, 0.f), (float)(W - 1));
    float y0 = fminf(fmaxf(y * H, 0.f), (float)(H - 1));
    float x1f = floorf(x0), x2f = ceilf(x0);
    float y1f = floorf(y0), y2f = ceilf(y0);
    int xi1 = (int)x1f, xi2 = (int)x2f, yi1 = (int)y1f, yi2 = (int)y2f;
    const float* fb = feat + ((size_t)b * C + c) * (size_t)(H * W);
    float Q11 = fb[yi1 * W + xi1];
    float Q12 = fb[yi2 * W + xi1];
    float Q21 = fb[yi1 * W + xi2];
    float Q22 = fb[yi2 * W + xi2];
    float wx2 = x2f - x0, wx1 = x0 - x1f;
    float wy2 = y2f - y0, wy1 = y0 - y1f;
    float r = wx2 * wy2 * Q11 + wx1 * wy2 * Q21
            + wx2 * wy1 * Q12 + wx1 * wy1 * Q22;
    out[m * ldout + c] = __float2bfloat16(r);
}

// ---------------------------------------------------------------------------
// copy 3 fp32 point coords per row into a bf16 buffer (cols 0..2)
__global__ __launch_bounds__(256) void copy3_kernel(
    const float* __restrict__ pts, int row0, int Mc,
    bf16* __restrict__ dst, int dld)
{
    int m = blockIdx.x * 256 + threadIdx.x;
    if (m >= Mc) return;
    const float* p = pts + (size_t)(row0 + m) * 3;
    bf16* d = dst + (size_t)m * dld;
    d[0] = __float2bfloat16(p[0]);
    d[1] = __float2bfloat16(p[1]);
    d[2] = __float2bfloat16(p[2]);
}

// ---------------------------------------------------------------------------
// out[row0+m,:] = x3[m,:] @ d4w^T + d4b + points[row0+m,:]   (x3 pre-relu'd)
__global__ __launch_bounds__(256) void final_kernel(
    const bf16* __restrict__ x3, const float* __restrict__ w,
    const float* __restrict__ bb, const float* __restrict__ points,
    int row0, int Mc, float* __restrict__ out)
{
    size_t m = (size_t)blockIdx.x * 256 + threadIdx.x;
    if (m >= (size_t)Mc) return;
    size_t gm = (size_t)row0 + m;
    float a0 = bb[0], a1 = bb[1], a2 = bb[2];
    const bf16* x = x3 + m * 128;
    #pragma unroll 4
    for (int k = 0; k < 128; ++k) {
        float v = __bfloat162float(x[k]);
        a0 += v * w[k];
        a1 += v * w[128 + k];
        a2 += v * w[256 + k];
    }
    out[gm * 3 + 0] = a0 + points[gm * 3 + 0];
    out[gm * 3 + 1] = a1 + points[gm * 3 + 1];
    out[gm * 3 + 2] = a2 + points[gm * 3 + 2];
}

// ---------------------------------------------------------------------------
extern "C" void kernel_launch(void* const* d_in, const int* in_sizes, int n_in,
                              void* d_out, int out_size, void* d_ws, size_t ws_size,
                              hipStream_t stream)
{
    const float* points = (const float*)d_in[0];
    const float* feat2  = (const float*)d_in[1];
    const float* feat3  = (const float*)d_in[2];
    const float* feat4  = (const float*)d_in[3];
    const float* feat5  = (const float*)d_in[4];
    const float* pmat   = (const float*)d_in[5];
    const float* b0w1 = (const float*)d_in[6];  const float* b0b1 = (const float*)d_in[7];
    const float* b0w2 = (const float*)d_in[8];  const float* b0b2 = (const float*)d_in[9];
    const float* t0w  = (const float*)d_in[10]; const float* t0b  = (const float*)d_in[11];
    const float* b1w1 = (const float*)d_in[12]; const float* b1b1 = (const float*)d_in[13];
    const float* b1w2 = (const float*)d_in[14]; const float* b1b2 = (const float*)d_in[15];
    const float* t1w  = (const float*)d_in[16]; const float* t1b  = (const float*)d_in[17];
    const float* b2w1 = (const float*)d_in[18]; const float* b2b1 = (const float*)d_in[19];
    const float* b2w2 = (const float*)d_in[20]; const float* b2b2 = (const float*)d_in[21];
    const float* t2w  = (const float*)d_in[22]; const float* t2b  = (const float*)d_in[23];
    const float* b3w1 = (const float*)d_in[24]; const float* b3b1 = (const float*)d_in[25];
    const float* b3w2 = (const float*)d_in[26]; const float* b3b2 = (const float*)d_in[27];
    const float* t3w  = (const float*)d_in[28]; const float* t3b  = (const float*)d_in[29];
    const float* d1w  = (const float*)d_in[30]; const float* d1b  = (const float*)d_in[31];
    const float* d2w  = (const float*)d_in[32]; const float* d2b  = (const float*)d_in[33];
    const float* d3w  = (const float*)d_in[34]; const float* d3b  = (const float*)d_in[35];
    const float* d4w  = (const float*)d_in[36]; const float* d4b  = (const float*)d_in[37];

    // ---- fp32 shared region ----
    float* wsf = (float*)d_ws;
    float* biasTot = wsf;                  // 512
    float* smean   = wsf + 512;            // 7680
    float* sscale  = smean + 7680;         // 7680
    float* foldtmp = sscale + 7680;        // 8 * 512 * 960
    const size_t F32_FLOATS = 512 + 2 * 7680 + (size_t)8 * 512 * 960;
    float* mean2 = smean, *mean3 = smean + 512, *mean4 = smean + 1536, *mean5 = smean + 3584;
    float* scl2 = sscale, *scl3 = sscale + 512, *scl4 = sscale + 1536, *scl5 = sscale + 3584;

    // ---- bf16 shared region: packed weights ----
    bf16* wb = (bf16*)(wsf + F32_FLOATS);
    bf16* Wd1   = wb;                       // 512 x 1952
    bf16* b0w1p = Wd1   + (size_t)512 * 1952;  // 64 x 32 (cols 3..31 zero)
    bf16* b0w2b = b0w1p + 64 * 32;          // 64 x 64
    bf16* b1w1b = b0w2b + 64 * 64;          // 128 x 64
    bf16* b1w2b = b1w1b + 128 * 64;         // 128 x 128
    bf16* b2w1b = b1w2b + 128 * 128;        // 256 x 128
    bf16* b2w2b = b2w1b + 256 * 128;        // 256 x 256
    bf16* b3w1b = b2w2b + 256 * 256;        // 512 x 256
    bf16* b3w2b = b3w1b + 512 * 256;        // 512 x 512
    bf16* d2wb  = b3w2b + (size_t)512 * 512; // 256 x 512
    bf16* d3wb  = d2wb  + (size_t)256 * 512; // 128 x 256
    const size_t SHARED_BF = (size_t)512 * 1952 + 64 * 32 + 64 * 64 + 128 * 64
        + 128 * 128 + 256 * 128 + 256 * 256 + (size_t)512 * 256
        + (size_t)512 * 512 + (size_t)256 * 512 + 128 * 256;   // 1,685,504

    const size_t SHARED_BYTES = F32_FLOATS * 4 + SHARED_BF * 2;

    // ---- chunking: per-row bf16 = 32+512+64+128+256+512+1952+512+256+128 = 4352
    const size_t PER_ROW_BYTES = 4352 * 2;
    size_t avail = (ws_size > SHARED_BYTES) ? ws_size - SHARED_BYTES : 0;
    int nch = 1;
    while (nch < 512 && (size_t)(MTOT / nch) * PER_ROW_BYTES > avail) nch <<= 1;
    const int Mc = MTOT / nch;

    bf16* cb = wb + SHARED_BF;
    bf16* ptsb  = cb;                          // Mc x 32
    bf16* hbuf  = ptsb  + (size_t)Mc * 32;     // Mc x <=512
    bf16* pc0   = hbuf  + (size_t)Mc * 512;    // Mc x 64
    bf16* pc1   = pc0   + (size_t)Mc * 64;     // Mc x 128
    bf16* pc2   = pc1   + (size_t)Mc * 128;    // Mc x 256
    bf16* pc3   = pc2   + (size_t)Mc * 256;    // Mc x 512
    bf16* feats = pc3   + (size_t)Mc * 512;    // Mc x 1952
    bf16* x1r   = feats + (size_t)Mc * 1952;   // Mc x 512
    bf16* x2    = x1r   + (size_t)Mc * 512;    // Mc x 256
    bf16* x3    = x2    + (size_t)Mc * 256;    // Mc x 128

    // ---- prep: stats ----
    stats_kernel<<<8 * 64,  256, 0, stream>>>(feat2, 112 * 112, mean2, scl2);
    stats_kernel<<<8 * 128, 256, 0, stream>>>(feat3, 56 * 56,  mean3, scl3);
    stats_kernel<<<8 * 256, 256, 0, stream>>>(feat4, 28 * 28,  mean4, scl4);
    stats_kernel<<<8 * 512, 256, 0, stream>>>(feat5, 14 * 14,  mean5, scl5);

    // ---- prep: weight conversions (one batched launch) ----
    ConvArgs ca;
    int nd = 0;
    auto addc = [&](const float* s, bf16* d, int sld, int dld, int r, int c) {
        ca.d[nd++] = ConvDesc{ s, d, sld, dld, r, c };
    };
    addc(b0w1, b0w1p, 3, 32, 64, 3);
    addc(nullptr, b0w1p + 3, 0, 32, 64, 29);        // zero pad cols 3..31
    addc(b0w2, b0w2b, 64, 64, 64, 64);
    addc(b1w1, b1w1b, 64, 64, 128, 64);
    addc(b1w2, b1w2b, 128, 128, 128, 128);
    addc(b2w1, b2w1b, 128, 128, 256, 128);
    addc(b2w2, b2w2b, 256, 256, 256, 256);
    addc(b3w1, b3w1b, 256, 256, 512, 256);
    addc(b3w2, b3w2b, 512, 512, 512, 512);
    addc(d2w, d2wb, 512, 512, 256, 512);
    addc(d3w, d3wb, 256, 256, 128, 256);
    addc(d1w + 960,  Wd1 + 960,  1923, 1952, 512, 64);   // proj2 chunk
    addc(d1w + 1024, Wd1 + 1024, 1923, 1952, 512, 128);  // proj3
    addc(d1w + 1152, Wd1 + 1152, 1923, 1952, 512, 256);  // proj4
    addc(d1w + 1408, Wd1 + 1408, 1923, 1952, 512, 512);  // proj5
    addc(d1w + 1920, Wd1 + 1920, 1923, 1952, 512, 3);    // points cols
    addc(nullptr,    Wd1 + 1923, 0,    1952, 512, 29);   // zero pad 1923..1951
    ca.n = nd;
    conv_batch<<<dim3(64, nd), 256, 0, stream>>>(ca);

    // ---- prep: split-K fold (680 blocks, one launch) + convert ----
    FoldArgs fa;
    fa.d[0] = FoldDesc{ 0,   t0w, 64,  0,   0,   1, 1 };
    fa.d[1] = FoldDesc{ 64,  t1w, 128, 64,  8,   2, 2 };
    fa.d[2] = FoldDesc{ 192, t2w, 256, 192, 40,  4, 4 };
    fa.d[3] = FoldDesc{ 448, t3w, 512, 448, 168, 8, 8 };
    fold_splitk<<<680, 256, 0, stream>>>(d1w, foldtmp, fa);
    fold_convert<<<(512 * 960 + 255) / 256, 256, 0, stream>>>(foldtmp, Wd1);
    bias_all<<<512, 64, 0, stream>>>(d1w, d1b, t0b, t1b, t2b, t3b, biasTot);

    auto G = [&](const bf16* A, int lda, const bf16* Wt, int ldw,
                 const float* bias, bf16* Cout, int ldc, int N, int K) {
        if (N >= 128) {
            int gy = N / 128, gx = Mc / 128;
            gemm_bf16<128><<<gx * gy, 256, 0, stream>>>(A, lda, Wt, ldw, bias,
                                                        Cout, ldc, gx, gy, K);
        } else {
            int gy = N / 64, gx = Mc / 128;
            gemm_bf16<64><<<gx * gy, 256, 0, stream>>>(A, lda, Wt, ldw, bias,
                                                       Cout, ldc, gx, gy, K);
        }
    };

    // ---- per-chunk pipeline ----
    for (int ch = 0; ch < nch; ++ch) {
        const int row0 = ch * Mc;

        copy3_kernel<<<(Mc + 255) / 256, 256, 0, stream>>>(points, row0, Mc, ptsb, 32);

        // level 0
        G(ptsb, 32, b0w1p, 32, b0b1, hbuf, 64, 64, 32);
        G(hbuf, 64, b0w2b, 64, b0b2, pc0, 64, 64, 64);
        adain_kernel<<<Mc / 4, 256, 0, stream>>>(pc0, 64, row0, mean2, scl2, feats + 0, 1952);
        // level 1
        G(pc0, 64, b1w1b, 64, b1b1, hbuf, 128, 128, 64);
        G(hbuf, 128, b1w2b, 128, b1b2, pc1, 128, 128, 128);
        adain_kernel<<<Mc / 4, 256, 0, stream>>>(pc1, 128, row0, mean3, scl3, feats + 64, 1952);
        // level 2
        G(pc1, 128, b2w1b, 128, b2b1, hbuf, 256, 256, 128);
        G(hbuf, 256, b2w2b, 256, b2b2, pc2, 256, 256, 256);
        adain_kernel<<<Mc / 4, 256, 0, stream>>>(pc2, 256, row0, mean4, scl4, feats + 192, 1952);
        // level 3
        G(pc2, 256, b3w1b, 256, b3b1, hbuf, 512, 512, 256);
        G(hbuf, 512, b3w2b, 512, b3b2, pc3, 512, 512, 512);
        adain_kernel<<<Mc / 4, 256, 0, stream>>>(pc3, 512, row0, mean5, scl5, feats + 448, 1952);

        // projections into feats cols 960..1919
        size_t tot;
        tot = (size_t)Mc * 64;
        proj_kernel<<<(tot + 255) / 256, 256, 0, stream>>>(points, pmat, feat2, 64, 112, 112, row0, Mc, feats + 960, 1952);
        tot = (size_t)Mc * 128;
        proj_kernel<<<(tot + 255) / 256, 256, 0, stream>>>(points, pmat, feat3, 128, 56, 56, row0, Mc, feats + 1024, 1952);
        tot = (size_t)Mc * 256;
        proj_kernel<<<(tot + 255) / 256, 256, 0, stream>>>(points, pmat, feat4, 256, 28, 28, row0, Mc, feats + 1152, 1952);
        tot = (size_t)Mc * 512;
        proj_kernel<<<(tot + 255) / 256, 256, 0, stream>>>(points, pmat, feat5, 512, 14, 14, row0, Mc, feats + 1408, 1952);

        // points cols 1920..1922 (cols 1923..1951 of Wd1 are zero -> garbage ok)
        copy3_kernel<<<(Mc + 255) / 256, 256, 0, stream>>>(points, row0, Mc, feats + 1920, 1952);

        // head
        G(feats, 1952, Wd1, 1952, biasTot, x1r, 512, 512, 1952);  // relu(x1)
        G(x1r, 512, d2wb, 512, d2b, x2, 256, 256, 512);           // relu(x2)
        G(x2, 256, d3wb, 256, d3b, x3, 128, 128, 256);            // relu(x3)
        final_kernel<<<(Mc + 255) / 256, 256, 0, stream>>>(x3, d4w, d4b, points,
                                                           row0, Mc, (float*)d_out);
    }
}